// Round 10
// baseline (289.141 us; speedup 1.0000x reference)
//
#include <hip/hip_runtime.h>

#define FEAT_C 512
#define Hh 96
#define Ww 96
#define HW (Hh*Ww)
#define NB 8
#define OUTC 409

typedef __attribute__((ext_vector_type(8))) short short8;
typedef __attribute__((ext_vector_type(4))) short short4v;
typedef __attribute__((ext_vector_type(4))) float f32x4;
typedef __fp16 h2 __attribute__((ext_vector_type(2)));
typedef __fp16 h8 __attribute__((ext_vector_type(8)));

typedef __attribute__((address_space(1))) const unsigned int gu32;
typedef __attribute__((address_space(3))) unsigned int lu32;

// counted waitcnt + scheduler fence (guide T4 + rule #18)
#define VMCNT(N) do { asm volatile("s_waitcnt vmcnt(" #N ")" ::: "memory"); \
                      __builtin_amdgcn_sched_barrier(0); } while (0)
#define LGKM0()  do { asm volatile("s_waitcnt lgkmcnt(0)" ::: "memory"); \
                      __builtin_amdgcn_sched_barrier(0); } while (0)

__device__ inline ushort f2bf(float x) {
    unsigned u = __float_as_uint(x);
    u += 0x7fffu + ((u >> 16) & 1u);
    return (ushort)(u >> 16);
}

#if __has_builtin(__builtin_amdgcn_fdot2)
__device__ inline float FDOT2(h2 a, h2 b, float c) {
    return __builtin_amdgcn_fdot2(a, b, c, false);
}
#else
__device__ inline float FDOT2(h2 a, h2 b, float c) {
    return c + (float)a[0] * (float)b[0] + (float)a[1] * (float)b[1];
}
#endif

__device__ inline h2 pair(h8 v, int i) {
    switch (i) {
        case 0: return __builtin_shufflevector(v, v, 0, 1);
        case 1: return __builtin_shufflevector(v, v, 2, 3);
        case 2: return __builtin_shufflevector(v, v, 4, 5);
        default: return __builtin_shufflevector(v, v, 6, 7);
    }
}

// ============ kpack: normalize + transpose feature ========================
#define PKPX 32
__global__ __launch_bounds__(256) void kpack(const float* __restrict__ f,
                                             ushort* __restrict__ fnorm) {
    __shared__ ushort tr[PKPX * 512];      // 32 KB
    __shared__ float ssqp[8][PKPX];
    __shared__ float sinvs[PKPX];
    int tid = threadIdx.x;
    int g = tid >> 5, pl = tid & 31;
    int b = blockIdx.y;
    int p0 = blockIdx.x * PKPX;
    const float* fb = f + (size_t)b * FEAT_C * HW + p0 + pl;

    float ssq = 0.f;
#pragma unroll
    for (int q = 0; q < 8; ++q) {
        int u = g * 8 + q;
        float v[8];
#pragma unroll
        for (int j = 0; j < 8; ++j)
            v[j] = fb[(size_t)(u * 8 + j) * HW];
        h2 a0 = __builtin_amdgcn_cvt_pkrtz(v[0], v[1]);
        h2 a1 = __builtin_amdgcn_cvt_pkrtz(v[2], v[3]);
        h2 a2 = __builtin_amdgcn_cvt_pkrtz(v[4], v[5]);
        h2 a3 = __builtin_amdgcn_cvt_pkrtz(v[6], v[7]);
        ssq = FDOT2(a0, a0, ssq); ssq = FDOT2(a1, a1, ssq);
        ssq = FDOT2(a2, a2, ssq); ssq = FDOT2(a3, a3, ssq);
        h8 hv;
        hv[0] = a0[0]; hv[1] = a0[1]; hv[2] = a1[0]; hv[3] = a1[1];
        hv[4] = a2[0]; hv[5] = a2[1]; hv[6] = a3[0]; hv[7] = a3[1];
        int up = u ^ (pl & 7);
        *(h8*)&tr[pl * 512 + up * 8] = hv;
    }
    ssqp[g][pl] = ssq;
    __syncthreads();
    if (tid < PKPX) {
        float s = 0.f;
#pragma unroll
        for (int gg = 0; gg < 8; ++gg) s += ssqp[gg][tid];
        sinvs[tid] = 1.0f / fmaxf(sqrtf(s), 1e-12f);
    }
    __syncthreads();

    size_t ob = ((size_t)b * HW + p0) * 512;
#pragma unroll
    for (int i = 0; i < 8; ++i) {
        int t = tid + i * 256;
        int r = t >> 6, k = t & 63;
        h8 hv = *(const h8*)&tr[r * 512 + ((k ^ (r & 7)) * 8)];
        float s = sinvs[r];
        h2 o0 = __builtin_amdgcn_cvt_pkrtz((float)hv[0] * s, (float)hv[1] * s);
        h2 o1 = __builtin_amdgcn_cvt_pkrtz((float)hv[2] * s, (float)hv[3] * s);
        h2 o2 = __builtin_amdgcn_cvt_pkrtz((float)hv[4] * s, (float)hv[5] * s);
        h2 o3 = __builtin_amdgcn_cvt_pkrtz((float)hv[6] * s, (float)hv[7] * s);
        h8 ov;
        ov[0] = o0[0]; ov[1] = o0[1]; ov[2] = o1[0]; ov[3] = o1[1];
        ov[4] = o2[0]; ov[5] = o2[1]; ov[6] = o3[0]; ov[7] = o3[1];
        *(h8*)&fnorm[ob + (size_t)r * 512 + k * 8] = ov;
    }
}

// ============ kss4: self-similarity, 16x8 tile, vertical px-pairs =========
#define SS_NPX 240
__global__ __launch_bounds__(256) void kss4(const ushort* __restrict__ fnorm,
                                            float* __restrict__ out,
                                            ushort* __restrict__ sspk0) {
    __shared__ ushort tile[2][SS_NPX * 32];   // 2 x 15.36 KB
    int tid = threadIdx.x;
    int w = tid >> 6, lane = tid & 63;
    int s = lane >> 4, q = lane & 15;
    int x0 = blockIdx.x * 16, y0 = blockIdx.y * 8, b = blockIdx.z;

    // staging: 960 16B-units (240 px x 4), 4 tasks/thread, swizzled dst
    size_t t_src[4];
    int t_dst[4];
    bool t_ok[4];
#pragma unroll
    for (int k = 0; k < 4; ++k) {
        int task = tid + k * 256;
        t_ok[k] = false; t_src[k] = 0; t_dst[k] = -1;
        if (task < 960) {
            int px = task >> 2, u = task & 3;
            int hr = px / 20, hc = px % 20;
            int gy = y0 + hr - 2, gx = x0 + hc - 2;
            t_dst[k] = px * 32 + ((u ^ ((px >> 1) & 3)) * 8);
            if (gy >= 0 && gy < Hh && gx >= 0 && gx < Ww) {
                t_ok[k] = true;
                t_src[k] = ((size_t)b * HW + (size_t)gy * Ww + gx) * 512 + u * 8;
            }
        }
    }

    float acc0[25], acc1[25];
#pragma unroll
    for (int o = 0; o < 25; ++o) { acc0[o] = 0.f; acc1[o] = 0.f; }

    auto stage = [&](int chunk, int nbuf) {
        short8 v[4];
#pragma unroll
        for (int k = 0; k < 4; ++k) {
            v[k] = (short8)0;
            if (t_ok[k]) v[k] = *(const short8*)(fnorm + t_src[k] + chunk * 32);
        }
#pragma unroll
        for (int k = 0; k < 4; ++k)
            if (t_dst[k] >= 0)
                *(short8*)&tile[nbuf][t_dst[k]] = v[k];
    };

    auto compute = [&](int kb) {
        const ushort* tb = tile[kb];
        auto rd = [&](int px) -> h8 {
            return *(const h8*)&tb[px * 32 + ((s ^ ((px >> 1) & 3)) * 8)];
        };
        int pc0 = (2 * w + 2) * 20 + q + 2;
        h8 c0 = rd(pc0);
        h8 c1 = rd(pc0 + 20);
#pragma unroll
        for (int dxc = 0; dxc < 5; ++dxc) {
#pragma unroll
            for (int dyr = 0; dyr < 6; ++dyr) {
                int pn = (2 * w + dyr) * 20 + q + dxc;
                h8 nv = rd(pn);
                if (dyr < 5) {
                    float a = acc0[dxc * 5 + dyr];
                    a = FDOT2(pair(nv, 0), pair(c0, 0), a);
                    a = FDOT2(pair(nv, 1), pair(c0, 1), a);
                    a = FDOT2(pair(nv, 2), pair(c0, 2), a);
                    a = FDOT2(pair(nv, 3), pair(c0, 3), a);
                    acc0[dxc * 5 + dyr] = a;
                }
                if (dyr > 0) {
                    float a = acc1[dxc * 5 + dyr - 1];
                    a = FDOT2(pair(nv, 0), pair(c1, 0), a);
                    a = FDOT2(pair(nv, 1), pair(c1, 1), a);
                    a = FDOT2(pair(nv, 2), pair(c1, 2), a);
                    a = FDOT2(pair(nv, 3), pair(c1, 3), a);
                    acc1[dxc * 5 + dyr - 1] = a;
                }
            }
        }
    };

    stage(0, 0);
    __syncthreads();
    for (int c = 0; c < 16; ++c) {
        if (c < 15) stage(c + 1, (c + 1) & 1);
        compute(c & 1);
        __syncthreads();
    }

    // reduce across the 4 slabs (lane quarters)
#pragma unroll
    for (int o = 0; o < 25; ++o) {
        float v0 = acc0[o];
        v0 += __shfl_xor(v0, 16);
        v0 += __shfl_xor(v0, 32);
        acc0[o] = v0;
        float v1 = acc1[o];
        v1 += __shfl_xor(v1, 16);
        v1 += __shfl_xor(v1, 32);
        acc1[o] = v1;
    }
    if (s == 0) {
        int gy0 = y0 + 2 * w, gx = x0 + q;
        size_t pix0 = (size_t)b * HW + (size_t)gy0 * Ww + gx;
        size_t ob0 = (size_t)b * OUTC * HW + (size_t)gy0 * Ww + gx;
#pragma unroll
        for (int o = 0; o < 25; ++o) {
            out[ob0 + (size_t)o * HW] = acc0[o];
            out[ob0 + (size_t)o * HW + Ww] = acc1[o];
        }
        ushort pk0[32], pk1[32];
#pragma unroll
        for (int o = 0; o < 25; ++o) { pk0[o] = f2bf(acc0[o]); pk1[o] = f2bf(acc1[o]); }
#pragma unroll
        for (int o = 25; o < 32; ++o) { pk0[o] = 0; pk1[o] = 0; }
#pragma unroll
        for (int u = 0; u < 4; ++u) {
            *(short8*)&sspk0[pix0 * 32 + u * 8] = *(short8*)&pk0[u * 8];
            *(short8*)&sspk0[(pix0 + Ww) * 32 + u * 8] = *(short8*)&pk1[u * 8];
        }
    }
}

// ============ merged weight repack (wpk0 + wpk1 + zpad, one launch) =======
// wpk0: [9 t][256 oc][4 slot][8] bf16, slot s holds ic-unit u = s^((oc>>1)&3)
// wpk1: [8 chunk][3 ky][3 kx][128 oc][4 slot][8] bf16, same baked swizzle
__global__ __launch_bounds__(256) void kwpacks(const float* __restrict__ w0,
                                               const float* __restrict__ w1,
                                               ushort* __restrict__ wpk0,
                                               ushort* __restrict__ wpk1,
                                               ushort* __restrict__ zpad) {
    if (blockIdx.x == 0 && threadIdx.x < 32) zpad[threadIdx.x] = 0;
    if (blockIdx.x < 288) {
        int i = blockIdx.x * 256 + threadIdx.x;
        if (i >= 9 * 256 * 32) return;
        int t = i >> 13, oc = (i >> 5) & 255;
        int s = (i >> 3) & 3, ii = i & 7;
        int u = s ^ ((oc >> 1) & 3);
        int ic = u * 8 + ii;
        wpk0[i] = (ic < 25) ? f2bf(w0[(size_t)oc * 225 + ic * 9 + t]) : (ushort)0;
    } else {
        int i = (blockIdx.x - 288) * 256 + threadIdx.x;
        if (i >= 8 * 9 * 128 * 32) return;
        int ct = i >> 12;                 // (c*9 + t)
        int c = ct / 9, t = ct % 9;
        int oc = (i >> 5) & 127;
        int s = (i >> 3) & 3, ii = i & 7;
        int u = s ^ ((oc >> 1) & 3);
        int ic = c * 32 + u * 8 + ii;
        wpk1[i] = f2bf(w1[((size_t)oc * 256 + ic) * 9 + t]);
    }
}

// ============ kconv1m: 25->256 conv, WEIGHTS IN REGISTERS =================
#define C1NPX 180
__global__ __launch_bounds__(512, 2) void kconv1m(const ushort* __restrict__ sspk0,
                                                  const ushort* __restrict__ wpk0,
                                                  const float* __restrict__ b0,
                                                  float* __restrict__ outp,
                                                  ushort* __restrict__ sspk) {
    __shared__ ushort plds[C1NPX * 32];   // 11.52 KB
    int tid = threadIdx.x;
    int lane = tid & 63, wid = tid >> 6;
    int wM = wid >> 1, wN = wid & 1;
    int l15 = lane & 15, l4 = lane >> 4;
    int x0 = blockIdx.x * 16, y0 = blockIdx.y * 8, b = blockIdx.z;

    // pixel staging loads (issued first: 2 VMEM ops/thread)
    short8 pv[2]; int pdst[2];
#pragma unroll
    for (int k = 0; k < 2; ++k) {
        int task = tid + k * 512;
        pv[k] = (short8)0; pdst[k] = -1;
        if (task < 720) {
            int px = task >> 2, u = task & 3;
            int iy = px / 18, ix = px % 18;
            int gy = y0 + iy - 1, gx = x0 + ix - 1;
            pdst[k] = px * 32 + (u ^ ((px >> 1) & 3)) * 8;
            if (gy >= 0 && gy < Hh && gx >= 0 && gx < Ww)
                pv[k] = *(const short8*)(sspk0 +
                        ((size_t)b * HW + (size_t)gy * Ww + gx) * 32 + u * 8);
        }
    }

    // A-frag register loads: tap t -> 4 coalesced 1KB loads/wave
    int wslot = l4 ^ ((l15 >> 1) & 3);
    const ushort* abase = wpk0 + (size_t)(wM * 64 + l15) * 32 + wslot * 8;
    short8 sA[4], sB[4];
    auto aload = [&](int t, short8 (&S)[4]) {
#pragma unroll
        for (int mi = 0; mi < 4; ++mi)
            S[mi] = *(const short8*)(abase + (size_t)t * 8192 + mi * 512);
    };

    aload(0, sA);
    aload(1, sB);

    // write pixels to LDS (compiler auto-waits on pv), then one barrier
#pragma unroll
    for (int k = 0; k < 2; ++k)
        if (pdst[k] >= 0) *(short8*)&plds[pdst[k]] = pv[k];
    LGKM0();
    __builtin_amdgcn_s_barrier();

    f32x4 acc[4][4];
#pragma unroll
    for (int mi = 0; mi < 4; ++mi)
#pragma unroll
        for (int ni = 0; ni < 4; ++ni)
            acc[mi][ni] = (f32x4)0.f;

    auto compute = [&](const short8 (&S)[4], int ky, int kx) {
        short8 bv[4];
#pragma unroll
        for (int ni = 0; ni < 4; ++ni) {
            int ipx = (wN * 4 + ni + ky) * 18 + l15 + kx;
            bv[ni] = *(const short8*)&plds[ipx * 32
                    + ((l4 ^ ((ipx >> 1) & 3)) * 8)];
        }
#pragma unroll
        for (int mi = 0; mi < 4; ++mi)
#pragma unroll
            for (int ni = 0; ni < 4; ++ni)
                acc[mi][ni] = __builtin_amdgcn_mfma_f32_16x16x32_bf16(
                    S[mi], bv[ni], acc[mi][ni], 0, 0, 0);
    };

    // tap loop, barrier-free; A dbuf: even taps sA, odd taps sB
#pragma unroll
    for (int t = 0; t < 9; ++t) {
        if (t < 8) { VMCNT(4); } else { VMCNT(0); }
        int ky = t / 3, kx = t % 3;
        if ((t & 1) == 0) {
            compute(sA, ky, kx);
            if (t < 7) aload(t + 2, sA);
        } else {
            compute(sB, ky, kx);
            if (t < 7) aload(t + 2, sB);
        }
    }

    size_t ob = (size_t)b * OUTC * HW + (size_t)25 * HW;
    size_t pb = (size_t)b * HW;
#pragma unroll
    for (int mi = 0; mi < 4; ++mi)
#pragma unroll
        for (int ni = 0; ni < 4; ++ni) {
            int gy = y0 + wN * 4 + ni, gx = x0 + l15;
            int oc_b = wM * 64 + mi * 16 + l4 * 4;
            short4v hv;
#pragma unroll
            for (int r = 0; r < 4; ++r) {
                float v = fmaxf(acc[mi][ni][r] + b0[oc_b + r], 0.f);
                outp[ob + (size_t)(oc_b + r) * HW + (size_t)gy * Ww + gx] = v;
                hv[r] = (short)f2bf(v);
            }
            *(short4v*)&sspk[(pb + (size_t)gy * Ww + gx) * 256 + oc_b] = hv;
        }
}

// ============ kconv2n: 256->128 conv, 16x8, K-SPLIT waves =================
// 4 waves = wM (oc-half, 64 oc) x wK (K-half: ic-chunks 0-3 / 4-7). Each
// wave computes the FULL 128-px tile over its K-half -> A-frags distinct
// per wave: block weight traffic halves to the 576 KB minimum (was 2x
// duplicated across the old wN pair). B ds_reads/wave unchanged (8 ni x
// 9 taps x 4 chunks = 288). acc[4][8] (128 VGPR) + 2x12-frag A dbuf.
// Pixels: DMA chunk-pairs (t, t+4) into plds[2][2 x 6144]; ledger per
// wave: A=12/group, P=6/pair -> VMCNT 12/12/18, tail 12/12/0.
// Epilogue: 2-pass cross-wK f32 reduction through the dead pixel LDS.
#define NPX2 180
__global__ __launch_bounds__(256, 2) void kconv2n(const ushort* __restrict__ sspk,
                                                  const ushort* __restrict__ wpk,
                                                  const float* __restrict__ b1,
                                                  const ushort* __restrict__ zpad,
                                                  float* __restrict__ outp) {
    __shared__ ushort plds[2][12288];      // 2 bufs x 2 halves x 12 KB = 48 KB
    int tid = threadIdx.x;
    int lane = tid & 63, wid = tid >> 6;
    int wM = wid & 1, wK = wid >> 1;
    int l15 = lane & 15, l4 = lane >> 4;
    int x0 = blockIdx.x * 16, y0 = blockIdx.y * 8, b = blockIdx.z;

    f32x4 acc[4][8];
#pragma unroll
    for (int mi = 0; mi < 4; ++mi)
#pragma unroll
        for (int ni = 0; ni < 8; ++ni)
            acc[mi][ni] = (f32x4)0.f;

    // pixel DMA prep: 3 base tasks/thread (per ic-chunk); source
    // pre-swizzled (unit u = slot ^ ((px>>1)&3)); OOB lanes read zpad.
    const ushort* p_src[3];
    int p_ok[3];
#pragma unroll
    for (int k = 0; k < 3; ++k) {
        int task = tid + k * 256;
        int px = task >> 2, slot = task & 3;
        int u = slot ^ ((px >> 1) & 3);
        int iy = px / 18, ix = px % 18;
        int gy = y0 + iy - 1, gx = x0 + ix - 1;
        bool ok = (px < NPX2) && gy >= 0 && gy < Hh && gx >= 0 && gx < Ww;
        p_ok[k] = ok ? 1 : 0;
        p_src[k] = ok ? (sspk + ((size_t)b * HW + (size_t)gy * Ww + gx) * 256
                         + u * 8)
                      : zpad;
    }
    // stage ic-chunk c into buf, half c>>2 (3 ops/wave)
    auto pstage = [&](int c, int buf) {
#pragma unroll
        for (int k = 0; k < 3; ++k)
            __builtin_amdgcn_global_load_lds(
                (gu32*)(p_src[k] + (p_ok[k] ? c * 32 : 0)),
                (lu32*)&plds[buf][(c >> 2) * 6144 + (k * 256 + wid * 64) * 8],
                16, 0, 0);
    };

    // A-frag register loads: relative group r (0..11) -> global group
    // wK*12 + r; 12 x coalesced 1KB loads
    int wslot = l4 ^ ((l15 >> 1) & 3);
    const ushort* abase = wpk + (size_t)(wK * 12) * 12288
                        + (size_t)(wM * 64 + l15) * 32 + wslot * 8;
    short8 sA[12], sB[12];
    auto aload = [&](int r, short8 (&S)[12]) {
#pragma unroll
        for (int kx = 0; kx < 3; ++kx)
#pragma unroll
            for (int mi = 0; mi < 4; ++mi)
                S[kx * 4 + mi] = *(const short8*)(abase + (size_t)r * 12288
                                                  + kx * 4096 + mi * 512);
    };
    auto compute = [&](const short8 (&S)[12], const ushort* lbase, int ky) {
#pragma unroll
        for (int kx = 0; kx < 3; ++kx) {
            short8 bv[8];
#pragma unroll
            for (int ni = 0; ni < 8; ++ni) {
                int ipx = (ni + ky) * 18 + l15 + kx;
                bv[ni] = *(const short8*)&lbase[ipx * 32
                        + ((l4 ^ ((ipx >> 1) & 3)) * 8)];
            }
#pragma unroll
            for (int mi = 0; mi < 4; ++mi)
#pragma unroll
                for (int ni = 0; ni < 8; ++ni)
                    acc[mi][ni] = __builtin_amdgcn_mfma_f32_16x16x32_bf16(
                        S[kx * 4 + mi], bv[ni], acc[mi][ni], 0, 0, 0);
        }
    };

    // t-step: groups r=3t..3t+2; ledger (outstanding at entry = 30:
    // A_r[12], P_t[6], A_{r+1}[12]):
    auto tstep = [&](int t, short8 (&Scur)[12], short8 (&Salt)[12], bool last) {
        const ushort* lbase = &plds[t & 1][wK * 6144];
        int r = 3 * t;
        VMCNT(12);                         // retire P_t + A_r
        __builtin_amdgcn_s_barrier();
        compute(Scur, lbase, 0);
        aload(r + 2, Scur);
        VMCNT(12);                         // retire A_{r+1}
        compute(Salt, lbase, 1);
        if (!last) {
            aload(r + 3, Salt);
            pstage(t + 1, (t + 1) & 1);
            pstage(t + 5, (t + 1) & 1);
            VMCNT(18);                     // retire A_{r+2}
        } else {
            VMCNT(0);
        }
        compute(Scur, lbase, 2);
        if (!last) aload(r + 4, Scur);
    };

    // prologue: pixels chunk-pair (0,4) -> buf0; A groups 0,1
    pstage(0, 0);
    pstage(4, 0);
    aload(0, sA);
    aload(1, sB);

    tstep(0, sA, sB, false);
    tstep(1, sB, sA, false);
    tstep(2, sA, sB, false);
    tstep(3, sB, sA, true);

    // ---- cross-wK reduction through (dead) pixel LDS, 2 passes ----------
    float* red = (float*)plds;             // 48 KB = 12288 floats
    size_t ob = (size_t)b * OUTC * HW + (size_t)281 * HW;
    LGKM0();
    __builtin_amdgcn_s_barrier();          // all pixel reads done
#pragma unroll
    for (int p = 0; p < 2; ++p) {
        if (wK == 1) {
#pragma unroll
            for (int mh = 0; mh < 2; ++mh) {
                int mi = p * 2 + mh;
#pragma unroll
                for (int ni = 0; ni < 8; ++ni)
                    *(f32x4*)&red[wM * 4096 + mh * 2048 + ni * 256 + lane * 4]
                        = acc[mi][ni];
            }
        }
        LGKM0();
        __builtin_amdgcn_s_barrier();
        if (wK == 0) {
#pragma unroll
            for (int mh = 0; mh < 2; ++mh) {
                int mi = p * 2 + mh;
#pragma unroll
                for (int ni = 0; ni < 8; ++ni) {
                    f32x4 other = *(const f32x4*)&red[wM * 4096 + mh * 2048
                                                     + ni * 256 + lane * 4];
                    int gy = y0 + ni, gx = x0 + l15;
                    int oc_b = wM * 64 + mi * 16 + l4 * 4;
#pragma unroll
                    for (int r = 0; r < 4; ++r) {
                        float v = acc[mi][ni][r] + other[r] + b1[oc_b + r];
                        outp[ob + (size_t)(oc_b + r) * HW + (size_t)gy * Ww + gx]
                            = fmaxf(v, 0.f);
                    }
                }
            }
        }
        LGKM0();
        __builtin_amdgcn_s_barrier();
    }
}

extern "C" void kernel_launch(void* const* d_in, const int* in_sizes, int n_in,
                              void* d_out, int out_size, void* d_ws, size_t ws_size,
                              hipStream_t stream) {
    const float* feat = (const float*)d_in[0];
    const float* w0   = (const float*)d_in[1];
    const float* b0   = (const float*)d_in[2];
    const float* w1   = (const float*)d_in[3];
    const float* b1   = (const float*)d_in[4];
    float* out = (float*)d_out;

    // ws: wpk0 (147456) | wpk1 (589824) | sspk (37748736) | fnorm (75497472)
    //     | sspk0 (4718592) | zpad (64)
    ushort* wpk0  = (ushort*)d_ws;
    ushort* wpk1  = (ushort*)((char*)d_ws + 147456);
    ushort* sspk  = (ushort*)((char*)d_ws + 147456 + 589824);
    ushort* fnorm = (ushort*)((char*)d_ws + 147456 + 589824 + 37748736);
    ushort* sspk0 = (ushort*)((char*)d_ws + 147456 + 589824 + 37748736
                              + 75497472);
    ushort* zpad  = (ushort*)((char*)d_ws + 147456 + 589824 + 37748736
                              + 75497472 + 4718592);

    hipLaunchKernelGGL(kwpacks, dim3(1440), dim3(256), 0, stream, w0, w1, wpk0, wpk1, zpad);
    hipLaunchKernelGGL(kpack,   dim3(HW / PKPX, NB), dim3(256), 0, stream, feat, fnorm);
    hipLaunchKernelGGL(kss4,    dim3(6, 12, NB), dim3(256), 0, stream, fnorm, out, sspk0);
    hipLaunchKernelGGL(kconv1m, dim3(6, 12, NB), dim3(512), 0, stream, sspk0, wpk0, b0, out, sspk);
    hipLaunchKernelGGL(kconv2n, dim3(6, 12, NB), dim3(256), 0, stream, sspk, wpk1, b1, zpad, out);
}

// Round 12
// 186.902 us; speedup vs baseline: 1.5470x; 1.5470x over previous
//
#include <hip/hip_runtime.h>

#define FEAT_C 512
#define Hh 96
#define Ww 96
#define HW (Hh*Ww)
#define NB 8
#define OUTC 409

typedef __attribute__((ext_vector_type(8))) short short8;
typedef __attribute__((ext_vector_type(4))) short short4v;
typedef __attribute__((ext_vector_type(4))) float f32x4;
typedef __fp16 h2 __attribute__((ext_vector_type(2)));
typedef __fp16 h8 __attribute__((ext_vector_type(8)));

typedef __attribute__((address_space(1))) const unsigned int gu32;
typedef __attribute__((address_space(3))) unsigned int lu32;

// counted waitcnt + scheduler fence (guide T4 + rule #18)
#define VMCNT(N) do { asm volatile("s_waitcnt vmcnt(" #N ")" ::: "memory"); \
                      __builtin_amdgcn_sched_barrier(0); } while (0)
#define LGKM0()  do { asm volatile("s_waitcnt lgkmcnt(0)" ::: "memory"); \
                      __builtin_amdgcn_sched_barrier(0); } while (0)

__device__ inline ushort f2bf(float x) {
    unsigned u = __float_as_uint(x);
    u += 0x7fffu + ((u >> 16) & 1u);
    return (ushort)(u >> 16);
}

#if __has_builtin(__builtin_amdgcn_fdot2)
__device__ inline float FDOT2(h2 a, h2 b, float c) {
    return __builtin_amdgcn_fdot2(a, b, c, false);
}
#else
__device__ inline float FDOT2(h2 a, h2 b, float c) {
    return c + (float)a[0] * (float)b[0] + (float)a[1] * (float)b[1];
}
#endif

__device__ inline h2 pair(h8 v, int i) {
    switch (i) {
        case 0: return __builtin_shufflevector(v, v, 0, 1);
        case 1: return __builtin_shufflevector(v, v, 2, 3);
        case 2: return __builtin_shufflevector(v, v, 4, 5);
        default: return __builtin_shufflevector(v, v, 6, 7);
    }
}

// ============ kpack: normalize + transpose feature ========================
#define PKPX 32
__global__ __launch_bounds__(256) void kpack(const float* __restrict__ f,
                                             ushort* __restrict__ fnorm) {
    __shared__ ushort tr[PKPX * 512];      // 32 KB
    __shared__ float ssqp[8][PKPX];
    __shared__ float sinvs[PKPX];
    int tid = threadIdx.x;
    int g = tid >> 5, pl = tid & 31;
    int b = blockIdx.y;
    int p0 = blockIdx.x * PKPX;
    const float* fb = f + (size_t)b * FEAT_C * HW + p0 + pl;

    float ssq = 0.f;
#pragma unroll
    for (int q = 0; q < 8; ++q) {
        int u = g * 8 + q;
        float v[8];
#pragma unroll
        for (int j = 0; j < 8; ++j)
            v[j] = fb[(size_t)(u * 8 + j) * HW];
        h2 a0 = __builtin_amdgcn_cvt_pkrtz(v[0], v[1]);
        h2 a1 = __builtin_amdgcn_cvt_pkrtz(v[2], v[3]);
        h2 a2 = __builtin_amdgcn_cvt_pkrtz(v[4], v[5]);
        h2 a3 = __builtin_amdgcn_cvt_pkrtz(v[6], v[7]);
        ssq = FDOT2(a0, a0, ssq); ssq = FDOT2(a1, a1, ssq);
        ssq = FDOT2(a2, a2, ssq); ssq = FDOT2(a3, a3, ssq);
        h8 hv;
        hv[0] = a0[0]; hv[1] = a0[1]; hv[2] = a1[0]; hv[3] = a1[1];
        hv[4] = a2[0]; hv[5] = a2[1]; hv[6] = a3[0]; hv[7] = a3[1];
        int up = u ^ (pl & 7);
        *(h8*)&tr[pl * 512 + up * 8] = hv;
    }
    ssqp[g][pl] = ssq;
    __syncthreads();
    if (tid < PKPX) {
        float s = 0.f;
#pragma unroll
        for (int gg = 0; gg < 8; ++gg) s += ssqp[gg][tid];
        sinvs[tid] = 1.0f / fmaxf(sqrtf(s), 1e-12f);
    }
    __syncthreads();

    size_t ob = ((size_t)b * HW + p0) * 512;
#pragma unroll
    for (int i = 0; i < 8; ++i) {
        int t = tid + i * 256;
        int r = t >> 6, k = t & 63;
        h8 hv = *(const h8*)&tr[r * 512 + ((k ^ (r & 7)) * 8)];
        float s = sinvs[r];
        h2 o0 = __builtin_amdgcn_cvt_pkrtz((float)hv[0] * s, (float)hv[1] * s);
        h2 o1 = __builtin_amdgcn_cvt_pkrtz((float)hv[2] * s, (float)hv[3] * s);
        h2 o2 = __builtin_amdgcn_cvt_pkrtz((float)hv[4] * s, (float)hv[5] * s);
        h2 o3 = __builtin_amdgcn_cvt_pkrtz((float)hv[6] * s, (float)hv[7] * s);
        h8 ov;
        ov[0] = o0[0]; ov[1] = o0[1]; ov[2] = o1[0]; ov[3] = o1[1];
        ov[4] = o2[0]; ov[5] = o2[1]; ov[6] = o3[0]; ov[7] = o3[1];
        *(h8*)&fnorm[ob + (size_t)r * 512 + k * 8] = ov;
    }
}

// ============ kss4: self-similarity, 16x8 tile, vertical px-pairs =========
#define SS_NPX 240
__global__ __launch_bounds__(256) void kss4(const ushort* __restrict__ fnorm,
                                            float* __restrict__ out,
                                            ushort* __restrict__ sspk0) {
    __shared__ ushort tile[2][SS_NPX * 32];   // 2 x 15.36 KB
    int tid = threadIdx.x;
    int w = tid >> 6, lane = tid & 63;
    int s = lane >> 4, q = lane & 15;
    int x0 = blockIdx.x * 16, y0 = blockIdx.y * 8, b = blockIdx.z;

    // staging: 960 16B-units (240 px x 4), 4 tasks/thread, swizzled dst
    size_t t_src[4];
    int t_dst[4];
    bool t_ok[4];
#pragma unroll
    for (int k = 0; k < 4; ++k) {
        int task = tid + k * 256;
        t_ok[k] = false; t_src[k] = 0; t_dst[k] = -1;
        if (task < 960) {
            int px = task >> 2, u = task & 3;
            int hr = px / 20, hc = px % 20;
            int gy = y0 + hr - 2, gx = x0 + hc - 2;
            t_dst[k] = px * 32 + ((u ^ ((px >> 1) & 3)) * 8);
            if (gy >= 0 && gy < Hh && gx >= 0 && gx < Ww) {
                t_ok[k] = true;
                t_src[k] = ((size_t)b * HW + (size_t)gy * Ww + gx) * 512 + u * 8;
            }
        }
    }

    float acc0[25], acc1[25];
#pragma unroll
    for (int o = 0; o < 25; ++o) { acc0[o] = 0.f; acc1[o] = 0.f; }

    auto stage = [&](int chunk, int nbuf) {
        short8 v[4];
#pragma unroll
        for (int k = 0; k < 4; ++k) {
            v[k] = (short8)0;
            if (t_ok[k]) v[k] = *(const short8*)(fnorm + t_src[k] + chunk * 32);
        }
#pragma unroll
        for (int k = 0; k < 4; ++k)
            if (t_dst[k] >= 0)
                *(short8*)&tile[nbuf][t_dst[k]] = v[k];
    };

    auto compute = [&](int kb) {
        const ushort* tb = tile[kb];
        auto rd = [&](int px) -> h8 {
            return *(const h8*)&tb[px * 32 + ((s ^ ((px >> 1) & 3)) * 8)];
        };
        int pc0 = (2 * w + 2) * 20 + q + 2;
        h8 c0 = rd(pc0);
        h8 c1 = rd(pc0 + 20);
#pragma unroll
        for (int dxc = 0; dxc < 5; ++dxc) {
#pragma unroll
            for (int dyr = 0; dyr < 6; ++dyr) {
                int pn = (2 * w + dyr) * 20 + q + dxc;
                h8 nv = rd(pn);
                if (dyr < 5) {
                    float a = acc0[dxc * 5 + dyr];
                    a = FDOT2(pair(nv, 0), pair(c0, 0), a);
                    a = FDOT2(pair(nv, 1), pair(c0, 1), a);
                    a = FDOT2(pair(nv, 2), pair(c0, 2), a);
                    a = FDOT2(pair(nv, 3), pair(c0, 3), a);
                    acc0[dxc * 5 + dyr] = a;
                }
                if (dyr > 0) {
                    float a = acc1[dxc * 5 + dyr - 1];
                    a = FDOT2(pair(nv, 0), pair(c1, 0), a);
                    a = FDOT2(pair(nv, 1), pair(c1, 1), a);
                    a = FDOT2(pair(nv, 2), pair(c1, 2), a);
                    a = FDOT2(pair(nv, 3), pair(c1, 3), a);
                    acc1[dxc * 5 + dyr - 1] = a;
                }
            }
        }
    };

    stage(0, 0);
    __syncthreads();
    for (int c = 0; c < 16; ++c) {
        if (c < 15) stage(c + 1, (c + 1) & 1);
        compute(c & 1);
        __syncthreads();
    }

    // reduce across the 4 slabs (lane quarters)
#pragma unroll
    for (int o = 0; o < 25; ++o) {
        float v0 = acc0[o];
        v0 += __shfl_xor(v0, 16);
        v0 += __shfl_xor(v0, 32);
        acc0[o] = v0;
        float v1 = acc1[o];
        v1 += __shfl_xor(v1, 16);
        v1 += __shfl_xor(v1, 32);
        acc1[o] = v1;
    }
    if (s == 0) {
        int gy0 = y0 + 2 * w, gx = x0 + q;
        size_t pix0 = (size_t)b * HW + (size_t)gy0 * Ww + gx;
        size_t ob0 = (size_t)b * OUTC * HW + (size_t)gy0 * Ww + gx;
#pragma unroll
        for (int o = 0; o < 25; ++o) {
            out[ob0 + (size_t)o * HW] = acc0[o];
            out[ob0 + (size_t)o * HW + Ww] = acc1[o];
        }
        ushort pk0[32], pk1[32];
#pragma unroll
        for (int o = 0; o < 25; ++o) { pk0[o] = f2bf(acc0[o]); pk1[o] = f2bf(acc1[o]); }
#pragma unroll
        for (int o = 25; o < 32; ++o) { pk0[o] = 0; pk1[o] = 0; }
#pragma unroll
        for (int u = 0; u < 4; ++u) {
            *(short8*)&sspk0[pix0 * 32 + u * 8] = *(short8*)&pk0[u * 8];
            *(short8*)&sspk0[(pix0 + Ww) * 32 + u * 8] = *(short8*)&pk1[u * 8];
        }
    }
}

// ============ merged weight repack (wpk0 + wpk1 + zpad, one launch) =======
// wpk0: [9 t][256 oc][4 slot][8] bf16, slot s holds ic-unit u = s^((oc>>1)&3)
// wpk1: [8 chunk][3 ky][3 kx][128 oc][4 slot][8] bf16, same baked swizzle
__global__ __launch_bounds__(256) void kwpacks(const float* __restrict__ w0,
                                               const float* __restrict__ w1,
                                               ushort* __restrict__ wpk0,
                                               ushort* __restrict__ wpk1,
                                               ushort* __restrict__ zpad) {
    if (blockIdx.x == 0 && threadIdx.x < 32) zpad[threadIdx.x] = 0;
    if (blockIdx.x < 288) {
        int i = blockIdx.x * 256 + threadIdx.x;
        if (i >= 9 * 256 * 32) return;
        int t = i >> 13, oc = (i >> 5) & 255;
        int s = (i >> 3) & 3, ii = i & 7;
        int u = s ^ ((oc >> 1) & 3);
        int ic = u * 8 + ii;
        wpk0[i] = (ic < 25) ? f2bf(w0[(size_t)oc * 225 + ic * 9 + t]) : (ushort)0;
    } else {
        int i = (blockIdx.x - 288) * 256 + threadIdx.x;
        if (i >= 8 * 9 * 128 * 32) return;
        int ct = i >> 12;                 // (c*9 + t)
        int c = ct / 9, t = ct % 9;
        int oc = (i >> 5) & 127;
        int s = (i >> 3) & 3, ii = i & 7;
        int u = s ^ ((oc >> 1) & 3);
        int ic = c * 32 + u * 8 + ii;
        wpk1[i] = f2bf(w1[((size_t)oc * 256 + ic) * 9 + t]);
    }
}

// ============ kconv1m: 25->256 conv, WEIGHTS IN REGISTERS =================
#define C1NPX 180
__global__ __launch_bounds__(512, 2) void kconv1m(const ushort* __restrict__ sspk0,
                                                  const ushort* __restrict__ wpk0,
                                                  const float* __restrict__ b0,
                                                  float* __restrict__ outp,
                                                  ushort* __restrict__ sspk) {
    __shared__ ushort plds[C1NPX * 32];   // 11.52 KB
    int tid = threadIdx.x;
    int lane = tid & 63, wid = tid >> 6;
    int wM = wid >> 1, wN = wid & 1;
    int l15 = lane & 15, l4 = lane >> 4;
    int x0 = blockIdx.x * 16, y0 = blockIdx.y * 8, b = blockIdx.z;

    // pixel staging loads (issued first: 2 VMEM ops/thread)
    short8 pv[2]; int pdst[2];
#pragma unroll
    for (int k = 0; k < 2; ++k) {
        int task = tid + k * 512;
        pv[k] = (short8)0; pdst[k] = -1;
        if (task < 720) {
            int px = task >> 2, u = task & 3;
            int iy = px / 18, ix = px % 18;
            int gy = y0 + iy - 1, gx = x0 + ix - 1;
            pdst[k] = px * 32 + (u ^ ((px >> 1) & 3)) * 8;
            if (gy >= 0 && gy < Hh && gx >= 0 && gx < Ww)
                pv[k] = *(const short8*)(sspk0 +
                        ((size_t)b * HW + (size_t)gy * Ww + gx) * 32 + u * 8);
        }
    }

    // A-frag register loads: tap t -> 4 coalesced 1KB loads/wave
    int wslot = l4 ^ ((l15 >> 1) & 3);
    const ushort* abase = wpk0 + (size_t)(wM * 64 + l15) * 32 + wslot * 8;
    short8 sA[4], sB[4];
    auto aload = [&](int t, short8 (&S)[4]) {
#pragma unroll
        for (int mi = 0; mi < 4; ++mi)
            S[mi] = *(const short8*)(abase + (size_t)t * 8192 + mi * 512);
    };

    aload(0, sA);
    aload(1, sB);

    // write pixels to LDS (compiler auto-waits on pv), then one barrier
#pragma unroll
    for (int k = 0; k < 2; ++k)
        if (pdst[k] >= 0) *(short8*)&plds[pdst[k]] = pv[k];
    LGKM0();
    __builtin_amdgcn_s_barrier();

    f32x4 acc[4][4];
#pragma unroll
    for (int mi = 0; mi < 4; ++mi)
#pragma unroll
        for (int ni = 0; ni < 4; ++ni)
            acc[mi][ni] = (f32x4)0.f;

    auto compute = [&](const short8 (&S)[4], int ky, int kx) {
        short8 bv[4];
#pragma unroll
        for (int ni = 0; ni < 4; ++ni) {
            int ipx = (wN * 4 + ni + ky) * 18 + l15 + kx;
            bv[ni] = *(const short8*)&plds[ipx * 32
                    + ((l4 ^ ((ipx >> 1) & 3)) * 8)];
        }
#pragma unroll
        for (int mi = 0; mi < 4; ++mi)
#pragma unroll
            for (int ni = 0; ni < 4; ++ni)
                acc[mi][ni] = __builtin_amdgcn_mfma_f32_16x16x32_bf16(
                    S[mi], bv[ni], acc[mi][ni], 0, 0, 0);
    };

    // tap loop, barrier-free; A dbuf: even taps sA, odd taps sB
#pragma unroll
    for (int t = 0; t < 9; ++t) {
        if (t < 8) { VMCNT(4); } else { VMCNT(0); }
        int ky = t / 3, kx = t % 3;
        if ((t & 1) == 0) {
            compute(sA, ky, kx);
            if (t < 7) aload(t + 2, sA);
        } else {
            compute(sB, ky, kx);
            if (t < 7) aload(t + 2, sB);
        }
    }

    size_t ob = (size_t)b * OUTC * HW + (size_t)25 * HW;
    size_t pb = (size_t)b * HW;
#pragma unroll
    for (int mi = 0; mi < 4; ++mi)
#pragma unroll
        for (int ni = 0; ni < 4; ++ni) {
            int gy = y0 + wN * 4 + ni, gx = x0 + l15;
            int oc_b = wM * 64 + mi * 16 + l4 * 4;
            short4v hv;
#pragma unroll
            for (int r = 0; r < 4; ++r) {
                float v = fmaxf(acc[mi][ni][r] + b0[oc_b + r], 0.f);
                outp[ob + (size_t)(oc_b + r) * HW + (size_t)gy * Ww + gx] = v;
                hv[r] = (short)f2bf(v);
            }
            *(short4v*)&sspk[(pb + (size_t)gy * Ww + gx) * 256 + oc_b] = hv;
        }
}

// ============ kconv2n: 256->128 conv, 16x8, WEIGHTS IN REGISTERS ==========
// R8 structure + bijective XCD swizzle on a flattened 1D grid of 576
// blocks (576%8==0): swz=(idx&7)*72+(idx>>3) gives each XCD one batch's
// 72 tiles -> that batch's sspk (~4.7MB) stays L2-resident.
#define NPX2 180
__global__ __launch_bounds__(256, 2) void kconv2n(const ushort* __restrict__ sspk,
                                                  const ushort* __restrict__ wpk,
                                                  const float* __restrict__ b1,
                                                  const ushort* __restrict__ zpad,
                                                  float* __restrict__ outp) {
    __shared__ ushort plds[2][6144];       // 2 x 12 KB (768 units incl pad)
    int tid = threadIdx.x;
    int lane = tid & 63, wid = tid >> 6;
    int wM = wid >> 1, wN = wid & 1;
    int l15 = lane & 15, l4 = lane >> 4;
    int swz = (blockIdx.x & 7) * 72 + (blockIdx.x >> 3);
    int b = swz / 72;
    int rem = swz % 72;
    int y0 = (rem / 6) * 8, x0 = (rem % 6) * 16;

    f32x4 acc[4][4];
#pragma unroll
    for (int mi = 0; mi < 4; ++mi)
#pragma unroll
        for (int ni = 0; ni < 4; ++ni)
            acc[mi][ni] = (f32x4)0.f;

    // pixel DMA prep: 3 tasks/thread; source pre-swizzled (unit u = slot ^
    // ((px>>1)&3)) so linear DMA reproduces the swizzled LDS layout.
    const ushort* p_src[3];
    int p_ok[3];
#pragma unroll
    for (int k = 0; k < 3; ++k) {
        int task = tid + k * 256;
        int px = task >> 2, slot = task & 3;
        int u = slot ^ ((px >> 1) & 3);
        int iy = px / 18, ix = px % 18;
        int gy = y0 + iy - 1, gx = x0 + ix - 1;
        bool ok = (px < NPX2) && gy >= 0 && gy < Hh && gx >= 0 && gx < Ww;
        p_ok[k] = ok ? 1 : 0;
        p_src[k] = ok ? (sspk + ((size_t)b * HW + (size_t)gy * Ww + gx) * 256
                         + u * 8)
                      : zpad;
    }
    auto pstage = [&](int c, int buf) {       // 3 ops/wave (vmcnt P=3)
#pragma unroll
        for (int k = 0; k < 3; ++k)
            __builtin_amdgcn_global_load_lds(
                (gu32*)(p_src[k] + (p_ok[k] ? c * 32 : 0)),
                (lu32*)&plds[buf][(k * 256 + wid * 64) * 8], 16, 0, 0);
    };

    // A-frag register loads: group g -> 12 x global_load_dwordx4 (coalesced
    // 1 KB/instr), j = kx*4+mi
    int wslot = l4 ^ ((l15 >> 1) & 3);
    const ushort* abase = wpk + (size_t)(wM * 64 + l15) * 32 + wslot * 8;
    short8 sA[12], sB[12];
    auto aload = [&](int g, short8 (&S)[12]) {
#pragma unroll
        for (int kx = 0; kx < 3; ++kx)
#pragma unroll
            for (int mi = 0; mi < 4; ++mi)
                S[kx * 4 + mi] = *(const short8*)(abase + (size_t)g * 12288
                                                  + kx * 4096 + mi * 512);
    };
    auto compute = [&](const short8 (&S)[12], const ushort* lbase, int ky) {
#pragma unroll
        for (int kx = 0; kx < 3; ++kx) {
            short8 bv[4];
#pragma unroll
            for (int ni = 0; ni < 4; ++ni) {
                int oy = wN * 4 + ni;
                int ipx = (oy + ky) * 18 + l15 + kx;
                bv[ni] = *(const short8*)&lbase[ipx * 32
                        + ((l4 ^ ((ipx >> 1) & 3)) * 8)];
            }
#pragma unroll
            for (int mi = 0; mi < 4; ++mi)
#pragma unroll
                for (int ni = 0; ni < 4; ++ni)
                    acc[mi][ni] = __builtin_amdgcn_mfma_f32_16x16x32_bf16(
                        S[kx * 4 + mi], bv[ni], acc[mi][ni], 0, 0, 0);
        }
    };

    // Per-chunk schedule (steady-state outstanding at entry:
    // A_{3c}[12], P_c[3], A_{3c+1}[12]):
    //   VM(12): retire P_c + A_{3c}   -> barrier -> ky0(Scur)
    //   aload(3c+2 -> Scur); VM(12): retire A_{3c+1} -> ky1(Salt)
    //   aload(3c+3 -> Salt); pstage(c+1); VM(15): retire A_{3c+2} -> ky2(Scur)
    //   aload(3c+4 -> Scur)
    auto chunk = [&](int c, short8 (&Scur)[12], short8 (&Salt)[12], bool last) {
        const ushort* lbase = plds[c & 1];
        VMCNT(12);
        __builtin_amdgcn_s_barrier();
        compute(Scur, lbase, 0);
        aload(3 * c + 2, Scur);
        VMCNT(12);
        compute(Salt, lbase, 1);
        if (!last) {
            aload(3 * c + 3, Salt);
            pstage(c + 1, (c + 1) & 1);
            VMCNT(15);
        } else {
            VMCNT(0);
        }
        compute(Scur, lbase, 2);
        if (!last) aload(3 * c + 4, Scur);
    };

    // prologue: P0, A0 -> sA, A1 -> sB
    pstage(0, 0);
    aload(0, sA);
    aload(1, sB);

    for (int c2 = 0; c2 < 4; ++c2) {
        chunk(2 * c2,     sA, sB, false);
        chunk(2 * c2 + 1, sB, sA, c2 == 3);
    }

    size_t ob = (size_t)b * OUTC * HW + (size_t)281 * HW;
#pragma unroll
    for (int mi = 0; mi < 4; ++mi)
#pragma unroll
        for (int ni = 0; ni < 4; ++ni) {
            int gy = y0 + wN * 4 + ni, gx = x0 + l15;
#pragma unroll
            for (int r = 0; r < 4; ++r) {
                int oc = wM * 64 + mi * 16 + l4 * 4 + r;
                float v = acc[mi][ni][r] + b1[oc];
                outp[ob + (size_t)oc * HW + (size_t)gy * Ww + gx] = fmaxf(v, 0.f);
            }
        }
}

extern "C" void kernel_launch(void* const* d_in, const int* in_sizes, int n_in,
                              void* d_out, int out_size, void* d_ws, size_t ws_size,
                              hipStream_t stream) {
    const float* feat = (const float*)d_in[0];
    const float* w0   = (const float*)d_in[1];
    const float* b0   = (const float*)d_in[2];
    const float* w1   = (const float*)d_in[3];
    const float* b1   = (const float*)d_in[4];
    float* out = (float*)d_out;

    // ws: wpk0 (147456) | wpk1 (589824) | sspk (37748736) | fnorm (75497472)
    //     | sspk0 (4718592) | zpad (64)
    ushort* wpk0  = (ushort*)d_ws;
    ushort* wpk1  = (ushort*)((char*)d_ws + 147456);
    ushort* sspk  = (ushort*)((char*)d_ws + 147456 + 589824);
    ushort* fnorm = (ushort*)((char*)d_ws + 147456 + 589824 + 37748736);
    ushort* sspk0 = (ushort*)((char*)d_ws + 147456 + 589824 + 37748736
                              + 75497472);
    ushort* zpad  = (ushort*)((char*)d_ws + 147456 + 589824 + 37748736
                              + 75497472 + 4718592);

    hipLaunchKernelGGL(kwpacks, dim3(1440), dim3(256), 0, stream, w0, w1, wpk0, wpk1, zpad);
    hipLaunchKernelGGL(kpack,   dim3(HW / PKPX, NB), dim3(256), 0, stream, feat, fnorm);
    hipLaunchKernelGGL(kss4,    dim3(6, 12, NB), dim3(256), 0, stream, fnorm, out, sspk0);
    hipLaunchKernelGGL(kconv1m, dim3(6, 12, NB), dim3(512), 0, stream, sspk0, wpk0, b0, out, sspk);
    hipLaunchKernelGGL(kconv2n, dim3(576), dim3(256), 0, stream, sspk, wpk1, b1, zpad, out);
}

// Round 13
// 184.912 us; speedup vs baseline: 1.5637x; 1.0108x over previous
//
#include <hip/hip_runtime.h>

#define FEAT_C 512
#define Hh 96
#define Ww 96
#define HW (Hh*Ww)
#define NB 8
#define OUTC 409

typedef __attribute__((ext_vector_type(8))) short short8;
typedef __attribute__((ext_vector_type(4))) short short4v;
typedef __attribute__((ext_vector_type(4))) float f32x4;
typedef __fp16 h2 __attribute__((ext_vector_type(2)));
typedef __fp16 h8 __attribute__((ext_vector_type(8)));

typedef __attribute__((address_space(1))) const unsigned int gu32;
typedef __attribute__((address_space(3))) unsigned int lu32;

// counted waitcnt + scheduler fence (guide T4 + rule #18)
#define VMCNT(N) do { asm volatile("s_waitcnt vmcnt(" #N ")" ::: "memory"); \
                      __builtin_amdgcn_sched_barrier(0); } while (0)
#define LGKM0()  do { asm volatile("s_waitcnt lgkmcnt(0)" ::: "memory"); \
                      __builtin_amdgcn_sched_barrier(0); } while (0)

__device__ inline ushort f2bf(float x) {
    unsigned u = __float_as_uint(x);
    u += 0x7fffu + ((u >> 16) & 1u);
    return (ushort)(u >> 16);
}

#if __has_builtin(__builtin_amdgcn_fdot2)
__device__ inline float FDOT2(h2 a, h2 b, float c) {
    return __builtin_amdgcn_fdot2(a, b, c, false);
}
#else
__device__ inline float FDOT2(h2 a, h2 b, float c) {
    return c + (float)a[0] * (float)b[0] + (float)a[1] * (float)b[1];
}
#endif

__device__ inline h2 pair(h8 v, int i) {
    switch (i) {
        case 0: return __builtin_shufflevector(v, v, 0, 1);
        case 1: return __builtin_shufflevector(v, v, 2, 3);
        case 2: return __builtin_shufflevector(v, v, 4, 5);
        default: return __builtin_shufflevector(v, v, 6, 7);
    }
}

// XCD-bijective decode for the 576-tile kernels (6x12 tiles x 8 batches):
// bid&7 = XCD = batch; bid>>3 = tile within batch. Each XCD owns exactly
// one batch's 72 tiles -> per-batch operands stay L2-resident.
__device__ inline void tile576(int bid, int& b, int& y0, int& x0) {
    b = bid & 7;
    int rem = bid >> 3;
    y0 = (rem / 6) * 8;
    x0 = (rem % 6) * 16;
}

// ============ kpack: normalize + transpose feature ========================
#define PKPX 32
__global__ __launch_bounds__(256) void kpack(const float* __restrict__ f,
                                             ushort* __restrict__ fnorm) {
    __shared__ ushort tr[PKPX * 512];      // 32 KB
    __shared__ float ssqp[8][PKPX];
    __shared__ float sinvs[PKPX];
    int tid = threadIdx.x;
    int g = tid >> 5, pl = tid & 31;
    int b = blockIdx.y;
    int p0 = blockIdx.x * PKPX;
    const float* fb = f + (size_t)b * FEAT_C * HW + p0 + pl;

    float ssq = 0.f;
#pragma unroll
    for (int q = 0; q < 8; ++q) {
        int u = g * 8 + q;
        float v[8];
#pragma unroll
        for (int j = 0; j < 8; ++j)
            v[j] = fb[(size_t)(u * 8 + j) * HW];
        h2 a0 = __builtin_amdgcn_cvt_pkrtz(v[0], v[1]);
        h2 a1 = __builtin_amdgcn_cvt_pkrtz(v[2], v[3]);
        h2 a2 = __builtin_amdgcn_cvt_pkrtz(v[4], v[5]);
        h2 a3 = __builtin_amdgcn_cvt_pkrtz(v[6], v[7]);
        ssq = FDOT2(a0, a0, ssq); ssq = FDOT2(a1, a1, ssq);
        ssq = FDOT2(a2, a2, ssq); ssq = FDOT2(a3, a3, ssq);
        h8 hv;
        hv[0] = a0[0]; hv[1] = a0[1]; hv[2] = a1[0]; hv[3] = a1[1];
        hv[4] = a2[0]; hv[5] = a2[1]; hv[6] = a3[0]; hv[7] = a3[1];
        int up = u ^ (pl & 7);
        *(h8*)&tr[pl * 512 + up * 8] = hv;
    }
    ssqp[g][pl] = ssq;
    __syncthreads();
    if (tid < PKPX) {
        float s = 0.f;
#pragma unroll
        for (int gg = 0; gg < 8; ++gg) s += ssqp[gg][tid];
        sinvs[tid] = 1.0f / fmaxf(sqrtf(s), 1e-12f);
    }
    __syncthreads();

    size_t ob = ((size_t)b * HW + p0) * 512;
#pragma unroll
    for (int i = 0; i < 8; ++i) {
        int t = tid + i * 256;
        int r = t >> 6, k = t & 63;
        h8 hv = *(const h8*)&tr[r * 512 + ((k ^ (r & 7)) * 8)];
        float s = sinvs[r];
        h2 o0 = __builtin_amdgcn_cvt_pkrtz((float)hv[0] * s, (float)hv[1] * s);
        h2 o1 = __builtin_amdgcn_cvt_pkrtz((float)hv[2] * s, (float)hv[3] * s);
        h2 o2 = __builtin_amdgcn_cvt_pkrtz((float)hv[4] * s, (float)hv[5] * s);
        h2 o3 = __builtin_amdgcn_cvt_pkrtz((float)hv[6] * s, (float)hv[7] * s);
        h8 ov;
        ov[0] = o0[0]; ov[1] = o0[1]; ov[2] = o1[0]; ov[3] = o1[1];
        ov[4] = o2[0]; ov[5] = o2[1]; ov[6] = o3[0]; ov[7] = o3[1];
        *(h8*)&fnorm[ob + (size_t)r * 512 + k * 8] = ov;
    }
}

// ============ kss4: self-similarity, 16x8 tile, vertical px-pairs =========
#define SS_NPX 240
__global__ __launch_bounds__(256) void kss4(const ushort* __restrict__ fnorm,
                                            float* __restrict__ out,
                                            ushort* __restrict__ sspk0) {
    __shared__ ushort tile[2][SS_NPX * 32];   // 2 x 15.36 KB
    int tid = threadIdx.x;
    int w = tid >> 6, lane = tid & 63;
    int s = lane >> 4, q = lane & 15;
    int b, y0, x0;
    tile576(blockIdx.x, b, y0, x0);

    // staging: 960 16B-units (240 px x 4), 4 tasks/thread, swizzled dst
    size_t t_src[4];
    int t_dst[4];
    bool t_ok[4];
#pragma unroll
    for (int k = 0; k < 4; ++k) {
        int task = tid + k * 256;
        t_ok[k] = false; t_src[k] = 0; t_dst[k] = -1;
        if (task < 960) {
            int px = task >> 2, u = task & 3;
            int hr = px / 20, hc = px % 20;
            int gy = y0 + hr - 2, gx = x0 + hc - 2;
            t_dst[k] = px * 32 + ((u ^ ((px >> 1) & 3)) * 8);
            if (gy >= 0 && gy < Hh && gx >= 0 && gx < Ww) {
                t_ok[k] = true;
                t_src[k] = ((size_t)b * HW + (size_t)gy * Ww + gx) * 512 + u * 8;
            }
        }
    }

    float acc0[25], acc1[25];
#pragma unroll
    for (int o = 0; o < 25; ++o) { acc0[o] = 0.f; acc1[o] = 0.f; }

    auto stage = [&](int chunk, int nbuf) {
        short8 v[4];
#pragma unroll
        for (int k = 0; k < 4; ++k) {
            v[k] = (short8)0;
            if (t_ok[k]) v[k] = *(const short8*)(fnorm + t_src[k] + chunk * 32);
        }
#pragma unroll
        for (int k = 0; k < 4; ++k)
            if (t_dst[k] >= 0)
                *(short8*)&tile[nbuf][t_dst[k]] = v[k];
    };

    auto compute = [&](int kb) {
        const ushort* tb = tile[kb];
        auto rd = [&](int px) -> h8 {
            return *(const h8*)&tb[px * 32 + ((s ^ ((px >> 1) & 3)) * 8)];
        };
        int pc0 = (2 * w + 2) * 20 + q + 2;
        h8 c0 = rd(pc0);
        h8 c1 = rd(pc0 + 20);
#pragma unroll
        for (int dxc = 0; dxc < 5; ++dxc) {
#pragma unroll
            for (int dyr = 0; dyr < 6; ++dyr) {
                int pn = (2 * w + dyr) * 20 + q + dxc;
                h8 nv = rd(pn);
                if (dyr < 5) {
                    float a = acc0[dxc * 5 + dyr];
                    a = FDOT2(pair(nv, 0), pair(c0, 0), a);
                    a = FDOT2(pair(nv, 1), pair(c0, 1), a);
                    a = FDOT2(pair(nv, 2), pair(c0, 2), a);
                    a = FDOT2(pair(nv, 3), pair(c0, 3), a);
                    acc0[dxc * 5 + dyr] = a;
                }
                if (dyr > 0) {
                    float a = acc1[dxc * 5 + dyr - 1];
                    a = FDOT2(pair(nv, 0), pair(c1, 0), a);
                    a = FDOT2(pair(nv, 1), pair(c1, 1), a);
                    a = FDOT2(pair(nv, 2), pair(c1, 2), a);
                    a = FDOT2(pair(nv, 3), pair(c1, 3), a);
                    acc1[dxc * 5 + dyr - 1] = a;
                }
            }
        }
    };

    stage(0, 0);
    __syncthreads();
    for (int c = 0; c < 16; ++c) {
        if (c < 15) stage(c + 1, (c + 1) & 1);
        compute(c & 1);
        __syncthreads();
    }

    // reduce across the 4 slabs (lane quarters)
#pragma unroll
    for (int o = 0; o < 25; ++o) {
        float v0 = acc0[o];
        v0 += __shfl_xor(v0, 16);
        v0 += __shfl_xor(v0, 32);
        acc0[o] = v0;
        float v1 = acc1[o];
        v1 += __shfl_xor(v1, 16);
        v1 += __shfl_xor(v1, 32);
        acc1[o] = v1;
    }
    if (s == 0) {
        int gy0 = y0 + 2 * w, gx = x0 + q;
        size_t pix0 = (size_t)b * HW + (size_t)gy0 * Ww + gx;
        size_t ob0 = (size_t)b * OUTC * HW + (size_t)gy0 * Ww + gx;
#pragma unroll
        for (int o = 0; o < 25; ++o) {
            out[ob0 + (size_t)o * HW] = acc0[o];
            out[ob0 + (size_t)o * HW + Ww] = acc1[o];
        }
        ushort pk0[32], pk1[32];
#pragma unroll
        for (int o = 0; o < 25; ++o) { pk0[o] = f2bf(acc0[o]); pk1[o] = f2bf(acc1[o]); }
#pragma unroll
        for (int o = 25; o < 32; ++o) { pk0[o] = 0; pk1[o] = 0; }
#pragma unroll
        for (int u = 0; u < 4; ++u) {
            *(short8*)&sspk0[pix0 * 32 + u * 8] = *(short8*)&pk0[u * 8];
            *(short8*)&sspk0[(pix0 + Ww) * 32 + u * 8] = *(short8*)&pk1[u * 8];
        }
    }
}

// ============ merged weight repack (wpk0 + wpk1 + zpad, one launch) =======
// wpk0: [9 t][256 oc][4 slot][8] bf16, slot s holds ic-unit u = s^((oc>>1)&3)
// wpk1: [8 chunk][3 ky][3 kx][128 oc][4 slot][8] bf16, same baked swizzle
__global__ __launch_bounds__(256) void kwpacks(const float* __restrict__ w0,
                                               const float* __restrict__ w1,
                                               ushort* __restrict__ wpk0,
                                               ushort* __restrict__ wpk1,
                                               ushort* __restrict__ zpad) {
    if (blockIdx.x == 0 && threadIdx.x < 32) zpad[threadIdx.x] = 0;
    if (blockIdx.x < 288) {
        int i = blockIdx.x * 256 + threadIdx.x;
        if (i >= 9 * 256 * 32) return;
        int t = i >> 13, oc = (i >> 5) & 255;
        int s = (i >> 3) & 3, ii = i & 7;
        int u = s ^ ((oc >> 1) & 3);
        int ic = u * 8 + ii;
        wpk0[i] = (ic < 25) ? f2bf(w0[(size_t)oc * 225 + ic * 9 + t]) : (ushort)0;
    } else {
        int i = (blockIdx.x - 288) * 256 + threadIdx.x;
        if (i >= 8 * 9 * 128 * 32) return;
        int ct = i >> 12;                 // (c*9 + t)
        int c = ct / 9, t = ct % 9;
        int oc = (i >> 5) & 127;
        int s = (i >> 3) & 3, ii = i & 7;
        int u = s ^ ((oc >> 1) & 3);
        int ic = c * 32 + u * 8 + ii;
        wpk1[i] = f2bf(w1[((size_t)oc * 256 + ic) * 9 + t]);
    }
}

// ============ kconv1m: 25->256 conv, WEIGHTS IN REGISTERS =================
#define C1NPX 180
__global__ __launch_bounds__(512, 2) void kconv1m(const ushort* __restrict__ sspk0,
                                                  const ushort* __restrict__ wpk0,
                                                  const float* __restrict__ b0,
                                                  float* __restrict__ outp,
                                                  ushort* __restrict__ sspk) {
    __shared__ ushort plds[C1NPX * 32];   // 11.52 KB
    int tid = threadIdx.x;
    int lane = tid & 63, wid = tid >> 6;
    int wM = wid >> 1, wN = wid & 1;
    int l15 = lane & 15, l4 = lane >> 4;
    int b, y0, x0;
    tile576(blockIdx.x, b, y0, x0);

    // pixel staging loads (issued first: 2 VMEM ops/thread)
    short8 pv[2]; int pdst[2];
#pragma unroll
    for (int k = 0; k < 2; ++k) {
        int task = tid + k * 512;
        pv[k] = (short8)0; pdst[k] = -1;
        if (task < 720) {
            int px = task >> 2, u = task & 3;
            int iy = px / 18, ix = px % 18;
            int gy = y0 + iy - 1, gx = x0 + ix - 1;
            pdst[k] = px * 32 + (u ^ ((px >> 1) & 3)) * 8;
            if (gy >= 0 && gy < Hh && gx >= 0 && gx < Ww)
                pv[k] = *(const short8*)(sspk0 +
                        ((size_t)b * HW + (size_t)gy * Ww + gx) * 32 + u * 8);
        }
    }

    // A-frag register loads: tap t -> 4 coalesced 1KB loads/wave
    int wslot = l4 ^ ((l15 >> 1) & 3);
    const ushort* abase = wpk0 + (size_t)(wM * 64 + l15) * 32 + wslot * 8;
    short8 sA[4], sB[4];
    auto aload = [&](int t, short8 (&S)[4]) {
#pragma unroll
        for (int mi = 0; mi < 4; ++mi)
            S[mi] = *(const short8*)(abase + (size_t)t * 8192 + mi * 512);
    };

    aload(0, sA);
    aload(1, sB);

    // write pixels to LDS (compiler auto-waits on pv), then one barrier
#pragma unroll
    for (int k = 0; k < 2; ++k)
        if (pdst[k] >= 0) *(short8*)&plds[pdst[k]] = pv[k];
    LGKM0();
    __builtin_amdgcn_s_barrier();

    f32x4 acc[4][4];
#pragma unroll
    for (int mi = 0; mi < 4; ++mi)
#pragma unroll
        for (int ni = 0; ni < 4; ++ni)
            acc[mi][ni] = (f32x4)0.f;

    auto compute = [&](const short8 (&S)[4], int ky, int kx) {
        short8 bv[4];
#pragma unroll
        for (int ni = 0; ni < 4; ++ni) {
            int ipx = (wN * 4 + ni + ky) * 18 + l15 + kx;
            bv[ni] = *(const short8*)&plds[ipx * 32
                    + ((l4 ^ ((ipx >> 1) & 3)) * 8)];
        }
#pragma unroll
        for (int mi = 0; mi < 4; ++mi)
#pragma unroll
            for (int ni = 0; ni < 4; ++ni)
                acc[mi][ni] = __builtin_amdgcn_mfma_f32_16x16x32_bf16(
                    S[mi], bv[ni], acc[mi][ni], 0, 0, 0);
    };

    // tap loop, barrier-free; A dbuf: even taps sA, odd taps sB
#pragma unroll
    for (int t = 0; t < 9; ++t) {
        if (t < 8) { VMCNT(4); } else { VMCNT(0); }
        int ky = t / 3, kx = t % 3;
        if ((t & 1) == 0) {
            compute(sA, ky, kx);
            if (t < 7) aload(t + 2, sA);
        } else {
            compute(sB, ky, kx);
            if (t < 7) aload(t + 2, sB);
        }
    }

    size_t ob = (size_t)b * OUTC * HW + (size_t)25 * HW;
    size_t pb = (size_t)b * HW;
#pragma unroll
    for (int mi = 0; mi < 4; ++mi)
#pragma unroll
        for (int ni = 0; ni < 4; ++ni) {
            int gy = y0 + wN * 4 + ni, gx = x0 + l15;
            int oc_b = wM * 64 + mi * 16 + l4 * 4;
            short4v hv;
#pragma unroll
            for (int r = 0; r < 4; ++r) {
                float v = fmaxf(acc[mi][ni][r] + b0[oc_b + r], 0.f);
                outp[ob + (size_t)(oc_b + r) * HW + (size_t)gy * Ww + gx] = v;
                hv[r] = (short)f2bf(v);
            }
            *(short4v*)&sspk[(pb + (size_t)gy * Ww + gx) * 256 + oc_b] = hv;
        }
}

// ============ kconv2n: 256->128 conv, 16x8, WEIGHTS IN REGISTERS ==========
// R8 structure + bijective XCD swizzle (576 blocks, one batch per XCD).
#define NPX2 180
__global__ __launch_bounds__(256, 2) void kconv2n(const ushort* __restrict__ sspk,
                                                  const ushort* __restrict__ wpk,
                                                  const float* __restrict__ b1,
                                                  const ushort* __restrict__ zpad,
                                                  float* __restrict__ outp) {
    __shared__ ushort plds[2][6144];       // 2 x 12 KB (768 units incl pad)
    int tid = threadIdx.x;
    int lane = tid & 63, wid = tid >> 6;
    int wM = wid >> 1, wN = wid & 1;
    int l15 = lane & 15, l4 = lane >> 4;
    int b, y0, x0;
    tile576(blockIdx.x, b, y0, x0);

    f32x4 acc[4][4];
#pragma unroll
    for (int mi = 0; mi < 4; ++mi)
#pragma unroll
        for (int ni = 0; ni < 4; ++ni)
            acc[mi][ni] = (f32x4)0.f;

    // pixel DMA prep: 3 tasks/thread; source pre-swizzled (unit u = slot ^
    // ((px>>1)&3)) so linear DMA reproduces the swizzled LDS layout.
    const ushort* p_src[3];
    int p_ok[3];
#pragma unroll
    for (int k = 0; k < 3; ++k) {
        int task = tid + k * 256;
        int px = task >> 2, slot = task & 3;
        int u = slot ^ ((px >> 1) & 3);
        int iy = px / 18, ix = px % 18;
        int gy = y0 + iy - 1, gx = x0 + ix - 1;
        bool ok = (px < NPX2) && gy >= 0 && gy < Hh && gx >= 0 && gx < Ww;
        p_ok[k] = ok ? 1 : 0;
        p_src[k] = ok ? (sspk + ((size_t)b * HW + (size_t)gy * Ww + gx) * 256
                         + u * 8)
                      : zpad;
    }
    auto pstage = [&](int c, int buf) {       // 3 ops/wave (vmcnt P=3)
#pragma unroll
        for (int k = 0; k < 3; ++k)
            __builtin_amdgcn_global_load_lds(
                (gu32*)(p_src[k] + (p_ok[k] ? c * 32 : 0)),
                (lu32*)&plds[buf][(k * 256 + wid * 64) * 8], 16, 0, 0);
    };

    // A-frag register loads: group g -> 12 x global_load_dwordx4 (coalesced
    // 1 KB/instr), j = kx*4+mi
    int wslot = l4 ^ ((l15 >> 1) & 3);
    const ushort* abase = wpk + (size_t)(wM * 64 + l15) * 32 + wslot * 8;
    short8 sA[12], sB[12];
    auto aload = [&](int g, short8 (&S)[12]) {
#pragma unroll
        for (int kx = 0; kx < 3; ++kx)
#pragma unroll
            for (int mi = 0; mi < 4; ++mi)
                S[kx * 4 + mi] = *(const short8*)(abase + (size_t)g * 12288
                                                  + kx * 4096 + mi * 512);
    };
    auto compute = [&](const short8 (&S)[12], const ushort* lbase, int ky) {
#pragma unroll
        for (int kx = 0; kx < 3; ++kx) {
            short8 bv[4];
#pragma unroll
            for (int ni = 0; ni < 4; ++ni) {
                int oy = wN * 4 + ni;
                int ipx = (oy + ky) * 18 + l15 + kx;
                bv[ni] = *(const short8*)&lbase[ipx * 32
                        + ((l4 ^ ((ipx >> 1) & 3)) * 8)];
            }
#pragma unroll
            for (int mi = 0; mi < 4; ++mi)
#pragma unroll
                for (int ni = 0; ni < 4; ++ni)
                    acc[mi][ni] = __builtin_amdgcn_mfma_f32_16x16x32_bf16(
                        S[kx * 4 + mi], bv[ni], acc[mi][ni], 0, 0, 0);
        }
    };

    // Per-chunk schedule (steady-state outstanding at entry:
    // A_{3c}[12], P_c[3], A_{3c+1}[12]):
    //   VM(12): retire P_c + A_{3c}   -> barrier -> ky0(Scur)
    //   aload(3c+2 -> Scur); VM(12): retire A_{3c+1} -> ky1(Salt)
    //   aload(3c+3 -> Salt); pstage(c+1); VM(15): retire A_{3c+2} -> ky2(Scur)
    //   aload(3c+4 -> Scur)
    auto chunk = [&](int c, short8 (&Scur)[12], short8 (&Salt)[12], bool last) {
        const ushort* lbase = plds[c & 1];
        VMCNT(12);
        __builtin_amdgcn_s_barrier();
        compute(Scur, lbase, 0);
        aload(3 * c + 2, Scur);
        VMCNT(12);
        compute(Salt, lbase, 1);
        if (!last) {
            aload(3 * c + 3, Salt);
            pstage(c + 1, (c + 1) & 1);
            VMCNT(15);
        } else {
            VMCNT(0);
        }
        compute(Scur, lbase, 2);
        if (!last) aload(3 * c + 4, Scur);
    };

    // prologue: P0, A0 -> sA, A1 -> sB
    pstage(0, 0);
    aload(0, sA);
    aload(1, sB);

    for (int c2 = 0; c2 < 4; ++c2) {
        chunk(2 * c2,     sA, sB, false);
        chunk(2 * c2 + 1, sB, sA, c2 == 3);
    }

    size_t ob = (size_t)b * OUTC * HW + (size_t)281 * HW;
#pragma unroll
    for (int mi = 0; mi < 4; ++mi)
#pragma unroll
        for (int ni = 0; ni < 4; ++ni) {
            int gy = y0 + wN * 4 + ni, gx = x0 + l15;
#pragma unroll
            for (int r = 0; r < 4; ++r) {
                int oc = wM * 64 + mi * 16 + l4 * 4 + r;
                float v = acc[mi][ni][r] + b1[oc];
                outp[ob + (size_t)oc * HW + (size_t)gy * Ww + gx] = fmaxf(v, 0.f);
            }
        }
}

extern "C" void kernel_launch(void* const* d_in, const int* in_sizes, int n_in,
                              void* d_out, int out_size, void* d_ws, size_t ws_size,
                              hipStream_t stream) {
    const float* feat = (const float*)d_in[0];
    const float* w0   = (const float*)d_in[1];
    const float* b0   = (const float*)d_in[2];
    const float* w1   = (const float*)d_in[3];
    const float* b1   = (const float*)d_in[4];
    float* out = (float*)d_out;

    // ws: wpk0 (147456) | wpk1 (589824) | sspk (37748736) | fnorm (75497472)
    //     | sspk0 (4718592) | zpad (64)
    ushort* wpk0  = (ushort*)d_ws;
    ushort* wpk1  = (ushort*)((char*)d_ws + 147456);
    ushort* sspk  = (ushort*)((char*)d_ws + 147456 + 589824);
    ushort* fnorm = (ushort*)((char*)d_ws + 147456 + 589824 + 37748736);
    ushort* sspk0 = (ushort*)((char*)d_ws + 147456 + 589824 + 37748736
                              + 75497472);
    ushort* zpad  = (ushort*)((char*)d_ws + 147456 + 589824 + 37748736
                              + 75497472 + 4718592);

    hipLaunchKernelGGL(kwpacks, dim3(1440), dim3(256), 0, stream, w0, w1, wpk0, wpk1, zpad);
    hipLaunchKernelGGL(kpack,   dim3(HW / PKPX, NB), dim3(256), 0, stream, feat, fnorm);
    hipLaunchKernelGGL(kss4,    dim3(576), dim3(256), 0, stream, fnorm, out, sspk0);
    hipLaunchKernelGGL(kconv1m, dim3(576), dim3(512), 0, stream, sspk0, wpk0, b0, out, sspk);
    hipLaunchKernelGGL(kconv2n, dim3(576), dim3(256), 0, stream, sspk, wpk1, b1, zpad, out);
}

// Round 14
// 167.588 us; speedup vs baseline: 1.7253x; 1.1034x over previous
//
#include <hip/hip_runtime.h>

#define FEAT_C 512
#define Hh 96
#define Ww 96
#define HW (Hh*Ww)
#define NB 8
#define OUTC 409

typedef __attribute__((ext_vector_type(8))) short short8;
typedef __attribute__((ext_vector_type(4))) short short4v;
typedef __attribute__((ext_vector_type(4))) float f32x4;
typedef __fp16 h2 __attribute__((ext_vector_type(2)));
typedef __fp16 h8 __attribute__((ext_vector_type(8)));

typedef __attribute__((address_space(1))) const unsigned int gu32;
typedef __attribute__((address_space(3))) unsigned int lu32;

// counted waitcnt + scheduler fence (guide T4 + rule #18)
#define VMCNT(N) do { asm volatile("s_waitcnt vmcnt(" #N ")" ::: "memory"); \
                      __builtin_amdgcn_sched_barrier(0); } while (0)
#define LGKM0()  do { asm volatile("s_waitcnt lgkmcnt(0)" ::: "memory"); \
                      __builtin_amdgcn_sched_barrier(0); } while (0)

__device__ inline ushort f2bf(float x) {
    unsigned u = __float_as_uint(x);
    u += 0x7fffu + ((u >> 16) & 1u);
    return (ushort)(u >> 16);
}

#if __has_builtin(__builtin_amdgcn_fdot2)
__device__ inline float FDOT2(h2 a, h2 b, float c) {
    return __builtin_amdgcn_fdot2(a, b, c, false);
}
#else
__device__ inline float FDOT2(h2 a, h2 b, float c) {
    return c + (float)a[0] * (float)b[0] + (float)a[1] * (float)b[1];
}
#endif

__device__ inline h2 pair(h8 v, int i) {
    switch (i) {
        case 0: return __builtin_shufflevector(v, v, 0, 1);
        case 1: return __builtin_shufflevector(v, v, 2, 3);
        case 2: return __builtin_shufflevector(v, v, 4, 5);
        default: return __builtin_shufflevector(v, v, 6, 7);
    }
}

// XCD-bijective decode for the 576-tile kernels (6x12 tiles x 8 batches):
// bid&7 = XCD = batch; bid>>3 = tile within batch. Each XCD owns exactly
// one batch's 72 tiles -> per-batch operands stay L2-resident.
__device__ inline void tile576(int bid, int& b, int& y0, int& x0) {
    b = bid & 7;
    int rem = bid >> 3;
    y0 = (rem / 6) * 8;
    x0 = (rem % 6) * 16;
}

// ============ kpack: normalize + transpose feature ========================
#define PKPX 32
__global__ __launch_bounds__(256) void kpack(const float* __restrict__ f,
                                             ushort* __restrict__ fnorm) {
    __shared__ ushort tr[PKPX * 512];      // 32 KB
    __shared__ float ssqp[8][PKPX];
    __shared__ float sinvs[PKPX];
    int tid = threadIdx.x;
    int g = tid >> 5, pl = tid & 31;
    int b = blockIdx.y;
    int p0 = blockIdx.x * PKPX;
    const float* fb = f + (size_t)b * FEAT_C * HW + p0 + pl;

    float ssq = 0.f;
#pragma unroll
    for (int q = 0; q < 8; ++q) {
        int u = g * 8 + q;
        float v[8];
#pragma unroll
        for (int j = 0; j < 8; ++j)
            v[j] = fb[(size_t)(u * 8 + j) * HW];
        h2 a0 = __builtin_amdgcn_cvt_pkrtz(v[0], v[1]);
        h2 a1 = __builtin_amdgcn_cvt_pkrtz(v[2], v[3]);
        h2 a2 = __builtin_amdgcn_cvt_pkrtz(v[4], v[5]);
        h2 a3 = __builtin_amdgcn_cvt_pkrtz(v[6], v[7]);
        ssq = FDOT2(a0, a0, ssq); ssq = FDOT2(a1, a1, ssq);
        ssq = FDOT2(a2, a2, ssq); ssq = FDOT2(a3, a3, ssq);
        h8 hv;
        hv[0] = a0[0]; hv[1] = a0[1]; hv[2] = a1[0]; hv[3] = a1[1];
        hv[4] = a2[0]; hv[5] = a2[1]; hv[6] = a3[0]; hv[7] = a3[1];
        int up = u ^ (pl & 7);
        *(h8*)&tr[pl * 512 + up * 8] = hv;
    }
    ssqp[g][pl] = ssq;
    __syncthreads();
    if (tid < PKPX) {
        float s = 0.f;
#pragma unroll
        for (int gg = 0; gg < 8; ++gg) s += ssqp[gg][tid];
        sinvs[tid] = 1.0f / fmaxf(sqrtf(s), 1e-12f);
    }
    __syncthreads();

    size_t ob = ((size_t)b * HW + p0) * 512;
#pragma unroll
    for (int i = 0; i < 8; ++i) {
        int t = tid + i * 256;
        int r = t >> 6, k = t & 63;
        h8 hv = *(const h8*)&tr[r * 512 + ((k ^ (r & 7)) * 8)];
        float s = sinvs[r];
        h2 o0 = __builtin_amdgcn_cvt_pkrtz((float)hv[0] * s, (float)hv[1] * s);
        h2 o1 = __builtin_amdgcn_cvt_pkrtz((float)hv[2] * s, (float)hv[3] * s);
        h2 o2 = __builtin_amdgcn_cvt_pkrtz((float)hv[4] * s, (float)hv[5] * s);
        h2 o3 = __builtin_amdgcn_cvt_pkrtz((float)hv[6] * s, (float)hv[7] * s);
        h8 ov;
        ov[0] = o0[0]; ov[1] = o0[1]; ov[2] = o1[0]; ov[3] = o1[1];
        ov[4] = o2[0]; ov[5] = o2[1]; ov[6] = o3[0]; ov[7] = o3[1];
        *(h8*)&fnorm[ob + (size_t)r * 512 + k * 8] = ov;
    }
}

// ============ kss4: self-similarity, 16x8 tile, vertical px-pairs =========
#define SS_NPX 240
__global__ __launch_bounds__(256) void kss4(const ushort* __restrict__ fnorm,
                                            float* __restrict__ out,
                                            ushort* __restrict__ sspk0) {
    __shared__ ushort tile[2][SS_NPX * 32];   // 2 x 15.36 KB
    int tid = threadIdx.x;
    int w = tid >> 6, lane = tid & 63;
    int s = lane >> 4, q = lane & 15;
    int b, y0, x0;
    tile576(blockIdx.x, b, y0, x0);

    // staging: 960 16B-units (240 px x 4), 4 tasks/thread, swizzled dst
    size_t t_src[4];
    int t_dst[4];
    bool t_ok[4];
#pragma unroll
    for (int k = 0; k < 4; ++k) {
        int task = tid + k * 256;
        t_ok[k] = false; t_src[k] = 0; t_dst[k] = -1;
        if (task < 960) {
            int px = task >> 2, u = task & 3;
            int hr = px / 20, hc = px % 20;
            int gy = y0 + hr - 2, gx = x0 + hc - 2;
            t_dst[k] = px * 32 + ((u ^ ((px >> 1) & 3)) * 8);
            if (gy >= 0 && gy < Hh && gx >= 0 && gx < Ww) {
                t_ok[k] = true;
                t_src[k] = ((size_t)b * HW + (size_t)gy * Ww + gx) * 512 + u * 8;
            }
        }
    }

    float acc0[25], acc1[25];
#pragma unroll
    for (int o = 0; o < 25; ++o) { acc0[o] = 0.f; acc1[o] = 0.f; }

    auto stage = [&](int chunk, int nbuf) {
        short8 v[4];
#pragma unroll
        for (int k = 0; k < 4; ++k) {
            v[k] = (short8)0;
            if (t_ok[k]) v[k] = *(const short8*)(fnorm + t_src[k] + chunk * 32);
        }
#pragma unroll
        for (int k = 0; k < 4; ++k)
            if (t_dst[k] >= 0)
                *(short8*)&tile[nbuf][t_dst[k]] = v[k];
    };

    auto compute = [&](int kb) {
        const ushort* tb = tile[kb];
        auto rd = [&](int px) -> h8 {
            return *(const h8*)&tb[px * 32 + ((s ^ ((px >> 1) & 3)) * 8)];
        };
        int pc0 = (2 * w + 2) * 20 + q + 2;
        h8 c0 = rd(pc0);
        h8 c1 = rd(pc0 + 20);
#pragma unroll
        for (int dxc = 0; dxc < 5; ++dxc) {
#pragma unroll
            for (int dyr = 0; dyr < 6; ++dyr) {
                int pn = (2 * w + dyr) * 20 + q + dxc;
                h8 nv = rd(pn);
                if (dyr < 5) {
                    float a = acc0[dxc * 5 + dyr];
                    a = FDOT2(pair(nv, 0), pair(c0, 0), a);
                    a = FDOT2(pair(nv, 1), pair(c0, 1), a);
                    a = FDOT2(pair(nv, 2), pair(c0, 2), a);
                    a = FDOT2(pair(nv, 3), pair(c0, 3), a);
                    acc0[dxc * 5 + dyr] = a;
                }
                if (dyr > 0) {
                    float a = acc1[dxc * 5 + dyr - 1];
                    a = FDOT2(pair(nv, 0), pair(c1, 0), a);
                    a = FDOT2(pair(nv, 1), pair(c1, 1), a);
                    a = FDOT2(pair(nv, 2), pair(c1, 2), a);
                    a = FDOT2(pair(nv, 3), pair(c1, 3), a);
                    acc1[dxc * 5 + dyr - 1] = a;
                }
            }
        }
    };

    stage(0, 0);
    __syncthreads();
    for (int c = 0; c < 16; ++c) {
        if (c < 15) stage(c + 1, (c + 1) & 1);
        compute(c & 1);
        __syncthreads();
    }

    // reduce across the 4 slabs (lane quarters)
#pragma unroll
    for (int o = 0; o < 25; ++o) {
        float v0 = acc0[o];
        v0 += __shfl_xor(v0, 16);
        v0 += __shfl_xor(v0, 32);
        acc0[o] = v0;
        float v1 = acc1[o];
        v1 += __shfl_xor(v1, 16);
        v1 += __shfl_xor(v1, 32);
        acc1[o] = v1;
    }
    if (s == 0) {
        int gy0 = y0 + 2 * w, gx = x0 + q;
        size_t pix0 = (size_t)b * HW + (size_t)gy0 * Ww + gx;
        size_t ob0 = (size_t)b * OUTC * HW + (size_t)gy0 * Ww + gx;
#pragma unroll
        for (int o = 0; o < 25; ++o) {
            __builtin_nontemporal_store(acc0[o], &out[ob0 + (size_t)o * HW]);
            __builtin_nontemporal_store(acc1[o], &out[ob0 + (size_t)o * HW + Ww]);
        }
        ushort pk0[32], pk1[32];
#pragma unroll
        for (int o = 0; o < 25; ++o) { pk0[o] = f2bf(acc0[o]); pk1[o] = f2bf(acc1[o]); }
#pragma unroll
        for (int o = 25; o < 32; ++o) { pk0[o] = 0; pk1[o] = 0; }
#pragma unroll
        for (int u = 0; u < 4; ++u) {
            *(short8*)&sspk0[pix0 * 32 + u * 8] = *(short8*)&pk0[u * 8];
            *(short8*)&sspk0[(pix0 + Ww) * 32 + u * 8] = *(short8*)&pk1[u * 8];
        }
    }
}

// ============ merged weight repack (wpk0 + wpk1 + zpad, one launch) =======
// wpk0: [9 t][256 oc][4 slot][8] bf16, slot s holds ic-unit u = s^((oc>>1)&3)
// wpk1: [8 chunk][3 ky][3 kx][128 oc][4 slot][8] bf16, same baked swizzle
__global__ __launch_bounds__(256) void kwpacks(const float* __restrict__ w0,
                                               const float* __restrict__ w1,
                                               ushort* __restrict__ wpk0,
                                               ushort* __restrict__ wpk1,
                                               ushort* __restrict__ zpad) {
    if (blockIdx.x == 0 && threadIdx.x < 32) zpad[threadIdx.x] = 0;
    if (blockIdx.x < 288) {
        int i = blockIdx.x * 256 + threadIdx.x;
        if (i >= 9 * 256 * 32) return;
        int t = i >> 13, oc = (i >> 5) & 255;
        int s = (i >> 3) & 3, ii = i & 7;
        int u = s ^ ((oc >> 1) & 3);
        int ic = u * 8 + ii;
        wpk0[i] = (ic < 25) ? f2bf(w0[(size_t)oc * 225 + ic * 9 + t]) : (ushort)0;
    } else {
        int i = (blockIdx.x - 288) * 256 + threadIdx.x;
        if (i >= 8 * 9 * 128 * 32) return;
        int ct = i >> 12;                 // (c*9 + t)
        int c = ct / 9, t = ct % 9;
        int oc = (i >> 5) & 127;
        int s = (i >> 3) & 3, ii = i & 7;
        int u = s ^ ((oc >> 1) & 3);
        int ic = c * 32 + u * 8 + ii;
        wpk1[i] = f2bf(w1[((size_t)oc * 256 + ic) * 9 + t]);
    }
}

// ============ kconv1m: 25->256 conv, WEIGHTS IN REGISTERS =================
#define C1NPX 180
__global__ __launch_bounds__(512, 2) void kconv1m(const ushort* __restrict__ sspk0,
                                                  const ushort* __restrict__ wpk0,
                                                  const float* __restrict__ b0,
                                                  float* __restrict__ outp,
                                                  ushort* __restrict__ sspk) {
    __shared__ ushort plds[C1NPX * 32];   // 11.52 KB
    int tid = threadIdx.x;
    int lane = tid & 63, wid = tid >> 6;
    int wM = wid >> 1, wN = wid & 1;
    int l15 = lane & 15, l4 = lane >> 4;
    int b, y0, x0;
    tile576(blockIdx.x, b, y0, x0);

    // pixel staging loads (issued first: 2 VMEM ops/thread)
    short8 pv[2]; int pdst[2];
#pragma unroll
    for (int k = 0; k < 2; ++k) {
        int task = tid + k * 512;
        pv[k] = (short8)0; pdst[k] = -1;
        if (task < 720) {
            int px = task >> 2, u = task & 3;
            int iy = px / 18, ix = px % 18;
            int gy = y0 + iy - 1, gx = x0 + ix - 1;
            pdst[k] = px * 32 + (u ^ ((px >> 1) & 3)) * 8;
            if (gy >= 0 && gy < Hh && gx >= 0 && gx < Ww)
                pv[k] = *(const short8*)(sspk0 +
                        ((size_t)b * HW + (size_t)gy * Ww + gx) * 32 + u * 8);
        }
    }

    // A-frag register loads: tap t -> 4 coalesced 1KB loads/wave
    int wslot = l4 ^ ((l15 >> 1) & 3);
    const ushort* abase = wpk0 + (size_t)(wM * 64 + l15) * 32 + wslot * 8;
    short8 sA[4], sB[4];
    auto aload = [&](int t, short8 (&S)[4]) {
#pragma unroll
        for (int mi = 0; mi < 4; ++mi)
            S[mi] = *(const short8*)(abase + (size_t)t * 8192 + mi * 512);
    };

    aload(0, sA);
    aload(1, sB);

    // write pixels to LDS (compiler auto-waits on pv), then one barrier
#pragma unroll
    for (int k = 0; k < 2; ++k)
        if (pdst[k] >= 0) *(short8*)&plds[pdst[k]] = pv[k];
    LGKM0();
    __builtin_amdgcn_s_barrier();

    f32x4 acc[4][4];
#pragma unroll
    for (int mi = 0; mi < 4; ++mi)
#pragma unroll
        for (int ni = 0; ni < 4; ++ni)
            acc[mi][ni] = (f32x4)0.f;

    auto compute = [&](const short8 (&S)[4], int ky, int kx) {
        short8 bv[4];
#pragma unroll
        for (int ni = 0; ni < 4; ++ni) {
            int ipx = (wN * 4 + ni + ky) * 18 + l15 + kx;
            bv[ni] = *(const short8*)&plds[ipx * 32
                    + ((l4 ^ ((ipx >> 1) & 3)) * 8)];
        }
#pragma unroll
        for (int mi = 0; mi < 4; ++mi)
#pragma unroll
            for (int ni = 0; ni < 4; ++ni)
                acc[mi][ni] = __builtin_amdgcn_mfma_f32_16x16x32_bf16(
                    S[mi], bv[ni], acc[mi][ni], 0, 0, 0);
    };

    // tap loop, barrier-free; A dbuf: even taps sA, odd taps sB
#pragma unroll
    for (int t = 0; t < 9; ++t) {
        if (t < 8) { VMCNT(4); } else { VMCNT(0); }
        int ky = t / 3, kx = t % 3;
        if ((t & 1) == 0) {
            compute(sA, ky, kx);
            if (t < 7) aload(t + 2, sA);
        } else {
            compute(sB, ky, kx);
            if (t < 7) aload(t + 2, sB);
        }
    }

    size_t ob = (size_t)b * OUTC * HW + (size_t)25 * HW;
    size_t pb = (size_t)b * HW;
#pragma unroll
    for (int mi = 0; mi < 4; ++mi)
#pragma unroll
        for (int ni = 0; ni < 4; ++ni) {
            int gy = y0 + wN * 4 + ni, gx = x0 + l15;
            int oc_b = wM * 64 + mi * 16 + l4 * 4;
            short4v hv;
#pragma unroll
            for (int r = 0; r < 4; ++r) {
                float v = fmaxf(acc[mi][ni][r] + b0[oc_b + r], 0.f);
                __builtin_nontemporal_store(v,
                    &outp[ob + (size_t)(oc_b + r) * HW + (size_t)gy * Ww + gx]);
                hv[r] = (short)f2bf(v);
            }
            *(short4v*)&sspk[(pb + (size_t)gy * Ww + gx) * 256 + oc_b] = hv;
        }
}

// ============ kconv2n: 256->128 conv, 16x8, WEIGHTS IN REGISTERS ==========
// R8 structure + bijective XCD swizzle (576 blocks, one batch per XCD).
#define NPX2 180
__global__ __launch_bounds__(256, 2) void kconv2n(const ushort* __restrict__ sspk,
                                                  const ushort* __restrict__ wpk,
                                                  const float* __restrict__ b1,
                                                  const ushort* __restrict__ zpad,
                                                  float* __restrict__ outp) {
    __shared__ ushort plds[2][6144];       // 2 x 12 KB (768 units incl pad)
    int tid = threadIdx.x;
    int lane = tid & 63, wid = tid >> 6;
    int wM = wid >> 1, wN = wid & 1;
    int l15 = lane & 15, l4 = lane >> 4;
    int b, y0, x0;
    tile576(blockIdx.x, b, y0, x0);

    f32x4 acc[4][4];
#pragma unroll
    for (int mi = 0; mi < 4; ++mi)
#pragma unroll
        for (int ni = 0; ni < 4; ++ni)
            acc[mi][ni] = (f32x4)0.f;

    // pixel DMA prep: 3 tasks/thread; source pre-swizzled (unit u = slot ^
    // ((px>>1)&3)) so linear DMA reproduces the swizzled LDS layout.
    const ushort* p_src[3];
    int p_ok[3];
#pragma unroll
    for (int k = 0; k < 3; ++k) {
        int task = tid + k * 256;
        int px = task >> 2, slot = task & 3;
        int u = slot ^ ((px >> 1) & 3);
        int iy = px / 18, ix = px % 18;
        int gy = y0 + iy - 1, gx = x0 + ix - 1;
        bool ok = (px < NPX2) && gy >= 0 && gy < Hh && gx >= 0 && gx < Ww;
        p_ok[k] = ok ? 1 : 0;
        p_src[k] = ok ? (sspk + ((size_t)b * HW + (size_t)gy * Ww + gx) * 256
                         + u * 8)
                      : zpad;
    }
    auto pstage = [&](int c, int buf) {       // 3 ops/wave (vmcnt P=3)
#pragma unroll
        for (int k = 0; k < 3; ++k)
            __builtin_amdgcn_global_load_lds(
                (gu32*)(p_src[k] + (p_ok[k] ? c * 32 : 0)),
                (lu32*)&plds[buf][(k * 256 + wid * 64) * 8], 16, 0, 0);
    };

    // A-frag register loads: group g -> 12 x global_load_dwordx4 (coalesced
    // 1 KB/instr), j = kx*4+mi
    int wslot = l4 ^ ((l15 >> 1) & 3);
    const ushort* abase = wpk + (size_t)(wM * 64 + l15) * 32 + wslot * 8;
    short8 sA[12], sB[12];
    auto aload = [&](int g, short8 (&S)[12]) {
#pragma unroll
        for (int kx = 0; kx < 3; ++kx)
#pragma unroll
            for (int mi = 0; mi < 4; ++mi)
                S[kx * 4 + mi] = *(const short8*)(abase + (size_t)g * 12288
                                                  + kx * 4096 + mi * 512);
    };
    auto compute = [&](const short8 (&S)[12], const ushort* lbase, int ky) {
#pragma unroll
        for (int kx = 0; kx < 3; ++kx) {
            short8 bv[4];
#pragma unroll
            for (int ni = 0; ni < 4; ++ni) {
                int oy = wN * 4 + ni;
                int ipx = (oy + ky) * 18 + l15 + kx;
                bv[ni] = *(const short8*)&lbase[ipx * 32
                        + ((l4 ^ ((ipx >> 1) & 3)) * 8)];
            }
#pragma unroll
            for (int mi = 0; mi < 4; ++mi)
#pragma unroll
                for (int ni = 0; ni < 4; ++ni)
                    acc[mi][ni] = __builtin_amdgcn_mfma_f32_16x16x32_bf16(
                        S[kx * 4 + mi], bv[ni], acc[mi][ni], 0, 0, 0);
        }
    };

    // Per-chunk schedule (steady-state outstanding at entry:
    // A_{3c}[12], P_c[3], A_{3c+1}[12]):
    //   VM(12): retire P_c + A_{3c}   -> barrier -> ky0(Scur)
    //   aload(3c+2 -> Scur); VM(12): retire A_{3c+1} -> ky1(Salt)
    //   aload(3c+3 -> Salt); pstage(c+1); VM(15): retire A_{3c+2} -> ky2(Scur)
    //   aload(3c+4 -> Scur)
    auto chunk = [&](int c, short8 (&Scur)[12], short8 (&Salt)[12], bool last) {
        const ushort* lbase = plds[c & 1];
        VMCNT(12);
        __builtin_amdgcn_s_barrier();
        compute(Scur, lbase, 0);
        aload(3 * c + 2, Scur);
        VMCNT(12);
        compute(Salt, lbase, 1);
        if (!last) {
            aload(3 * c + 3, Salt);
            pstage(c + 1, (c + 1) & 1);
            VMCNT(15);
        } else {
            VMCNT(0);
        }
        compute(Scur, lbase, 2);
        if (!last) aload(3 * c + 4, Scur);
    };

    // prologue: P0, A0 -> sA, A1 -> sB
    pstage(0, 0);
    aload(0, sA);
    aload(1, sB);

    for (int c2 = 0; c2 < 4; ++c2) {
        chunk(2 * c2,     sA, sB, false);
        chunk(2 * c2 + 1, sB, sA, c2 == 3);
    }

    size_t ob = (size_t)b * OUTC * HW + (size_t)281 * HW;
#pragma unroll
    for (int mi = 0; mi < 4; ++mi)
#pragma unroll
        for (int ni = 0; ni < 4; ++ni) {
            int gy = y0 + wN * 4 + ni, gx = x0 + l15;
#pragma unroll
            for (int r = 0; r < 4; ++r) {
                int oc = wM * 64 + mi * 16 + l4 * 4 + r;
                float v = acc[mi][ni][r] + b1[oc];
                __builtin_nontemporal_store(fmaxf(v, 0.f),
                    &outp[ob + (size_t)oc * HW + (size_t)gy * Ww + gx]);
            }
        }
}

extern "C" void kernel_launch(void* const* d_in, const int* in_sizes, int n_in,
                              void* d_out, int out_size, void* d_ws, size_t ws_size,
                              hipStream_t stream) {
    const float* feat = (const float*)d_in[0];
    const float* w0   = (const float*)d_in[1];
    const float* b0   = (const float*)d_in[2];
    const float* w1   = (const float*)d_in[3];
    const float* b1   = (const float*)d_in[4];
    float* out = (float*)d_out;

    // ws: wpk0 (147456) | wpk1 (589824) | sspk (37748736) | fnorm (75497472)
    //     | sspk0 (4718592) | zpad (64)
    ushort* wpk0  = (ushort*)d_ws;
    ushort* wpk1  = (ushort*)((char*)d_ws + 147456);
    ushort* sspk  = (ushort*)((char*)d_ws + 147456 + 589824);
    ushort* fnorm = (ushort*)((char*)d_ws + 147456 + 589824 + 37748736);
    ushort* sspk0 = (ushort*)((char*)d_ws + 147456 + 589824 + 37748736
                              + 75497472);
    ushort* zpad  = (ushort*)((char*)d_ws + 147456 + 589824 + 37748736
                              + 75497472 + 4718592);

    hipLaunchKernelGGL(kwpacks, dim3(1440), dim3(256), 0, stream, w0, w1, wpk0, wpk1, zpad);
    hipLaunchKernelGGL(kpack,   dim3(HW / PKPX, NB), dim3(256), 0, stream, feat, fnorm);
    hipLaunchKernelGGL(kss4,    dim3(576), dim3(256), 0, stream, fnorm, out, sspk0);
    hipLaunchKernelGGL(kconv1m, dim3(576), dim3(512), 0, stream, sspk0, wpk0, b0, out, sspk);
    hipLaunchKernelGGL(kconv2n, dim3(576), dim3(256), 0, stream, sspk, wpk1, b1, zpad, out);
}

// Round 15
// 167.257 us; speedup vs baseline: 1.7287x; 1.0020x over previous
//
#include <hip/hip_runtime.h>

#define FEAT_C 512
#define Hh 96
#define Ww 96
#define HW (Hh*Ww)
#define NB 8
#define OUTC 409

typedef __attribute__((ext_vector_type(8))) short short8;
typedef __attribute__((ext_vector_type(4))) short short4v;
typedef __attribute__((ext_vector_type(4))) float f32x4;
typedef __fp16 h2 __attribute__((ext_vector_type(2)));
typedef __fp16 h8 __attribute__((ext_vector_type(8)));

typedef __attribute__((address_space(1))) const unsigned int gu32;
typedef __attribute__((address_space(3))) unsigned int lu32;

// counted waitcnt + scheduler fence (guide T4 + rule #18)
#define VMCNT(N) do { asm volatile("s_waitcnt vmcnt(" #N ")" ::: "memory"); \
                      __builtin_amdgcn_sched_barrier(0); } while (0)
#define LGKM0()  do { asm volatile("s_waitcnt lgkmcnt(0)" ::: "memory"); \
                      __builtin_amdgcn_sched_barrier(0); } while (0)

__device__ inline ushort f2bf(float x) {
    unsigned u = __float_as_uint(x);
    u += 0x7fffu + ((u >> 16) & 1u);
    return (ushort)(u >> 16);
}

#if __has_builtin(__builtin_amdgcn_fdot2)
__device__ inline float FDOT2(h2 a, h2 b, float c) {
    return __builtin_amdgcn_fdot2(a, b, c, false);
}
#else
__device__ inline float FDOT2(h2 a, h2 b, float c) {
    return c + (float)a[0] * (float)b[0] + (float)a[1] * (float)b[1];
}
#endif

__device__ inline h2 pair(h8 v, int i) {
    switch (i) {
        case 0: return __builtin_shufflevector(v, v, 0, 1);
        case 1: return __builtin_shufflevector(v, v, 2, 3);
        case 2: return __builtin_shufflevector(v, v, 4, 5);
        default: return __builtin_shufflevector(v, v, 6, 7);
    }
}

// XCD-bijective decode for the 576-tile kernels (6x12 tiles x 8 batches):
// bid&7 = XCD = batch; bid>>3 = tile within batch. Each XCD owns exactly
// one batch's 72 tiles -> per-batch operands stay L2-resident.
__device__ inline void tile576(int bid, int& b, int& y0, int& x0) {
    b = bid & 7;
    int rem = bid >> 3;
    y0 = (rem / 6) * 8;
    x0 = (rem % 6) * 16;
}

// ============ kpackw: normalize+transpose feature MERGED with weight =====
// repack (independent work, one launch). Blocks 0..2303: kpack path
// (b = bid/288, p0 = (bid%288)*32). Blocks 2304..: kwpacks path.
// feat reads are NT (single-use 120MB stream -> don't evict fnorm tail
// from per-XCD L2; kss4 reads it next).
#define PKPX 32
__global__ __launch_bounds__(256) void kpackw(const float* __restrict__ f,
                                              ushort* __restrict__ fnorm,
                                              const float* __restrict__ w0,
                                              const float* __restrict__ w1,
                                              ushort* __restrict__ wpk0,
                                              ushort* __restrict__ wpk1,
                                              ushort* __restrict__ zpad) {
    __shared__ ushort tr[PKPX * 512];      // 32 KB
    __shared__ float ssqp[8][PKPX];
    __shared__ float sinvs[PKPX];
    int tid = threadIdx.x;
    int bid = blockIdx.x;

    if (bid >= 2304) {
        // ---------------- weight repack path ----------------
        int wb = bid - 2304;
        if (wb == 0 && tid < 32) zpad[tid] = 0;
        if (wb < 288) {
            int i = wb * 256 + tid;
            if (i >= 9 * 256 * 32) return;
            int t = i >> 13, oc = (i >> 5) & 255;
            int s = (i >> 3) & 3, ii = i & 7;
            int u = s ^ ((oc >> 1) & 3);
            int ic = u * 8 + ii;
            wpk0[i] = (ic < 25) ? f2bf(w0[(size_t)oc * 225 + ic * 9 + t])
                                : (ushort)0;
        } else {
            int i = (wb - 288) * 256 + tid;
            if (i >= 8 * 9 * 128 * 32) return;
            int ct = i >> 12;                 // (c*9 + t)
            int c = ct / 9, t = ct % 9;
            int oc = (i >> 5) & 127;
            int s = (i >> 3) & 3, ii = i & 7;
            int u = s ^ ((oc >> 1) & 3);
            int ic = c * 32 + u * 8 + ii;
            wpk1[i] = f2bf(w1[((size_t)oc * 256 + ic) * 9 + t]);
        }
        return;
    }

    // ---------------- kpack path ----------------
    int g = tid >> 5, pl = tid & 31;
    int b = bid / 288;
    int p0 = (bid % 288) * PKPX;
    const float* fb = f + (size_t)b * FEAT_C * HW + p0 + pl;

    float ssq = 0.f;
#pragma unroll
    for (int q = 0; q < 8; ++q) {
        int u = g * 8 + q;
        float v[8];
#pragma unroll
        for (int j = 0; j < 8; ++j)
            v[j] = __builtin_nontemporal_load(&fb[(size_t)(u * 8 + j) * HW]);
        h2 a0 = __builtin_amdgcn_cvt_pkrtz(v[0], v[1]);
        h2 a1 = __builtin_amdgcn_cvt_pkrtz(v[2], v[3]);
        h2 a2 = __builtin_amdgcn_cvt_pkrtz(v[4], v[5]);
        h2 a3 = __builtin_amdgcn_cvt_pkrtz(v[6], v[7]);
        ssq = FDOT2(a0, a0, ssq); ssq = FDOT2(a1, a1, ssq);
        ssq = FDOT2(a2, a2, ssq); ssq = FDOT2(a3, a3, ssq);
        h8 hv;
        hv[0] = a0[0]; hv[1] = a0[1]; hv[2] = a1[0]; hv[3] = a1[1];
        hv[4] = a2[0]; hv[5] = a2[1]; hv[6] = a3[0]; hv[7] = a3[1];
        int up = u ^ (pl & 7);
        *(h8*)&tr[pl * 512 + up * 8] = hv;
    }
    ssqp[g][pl] = ssq;
    __syncthreads();
    if (tid < PKPX) {
        float s = 0.f;
#pragma unroll
        for (int gg = 0; gg < 8; ++gg) s += ssqp[gg][tid];
        sinvs[tid] = 1.0f / fmaxf(sqrtf(s), 1e-12f);
    }
    __syncthreads();

    size_t ob = ((size_t)b * HW + p0) * 512;
#pragma unroll
    for (int i = 0; i < 8; ++i) {
        int t = tid + i * 256;
        int r = t >> 6, k = t & 63;
        h8 hv = *(const h8*)&tr[r * 512 + ((k ^ (r & 7)) * 8)];
        float s = sinvs[r];
        h2 o0 = __builtin_amdgcn_cvt_pkrtz((float)hv[0] * s, (float)hv[1] * s);
        h2 o1 = __builtin_amdgcn_cvt_pkrtz((float)hv[2] * s, (float)hv[3] * s);
        h2 o2 = __builtin_amdgcn_cvt_pkrtz((float)hv[4] * s, (float)hv[5] * s);
        h2 o3 = __builtin_amdgcn_cvt_pkrtz((float)hv[6] * s, (float)hv[7] * s);
        h8 ov;
        ov[0] = o0[0]; ov[1] = o0[1]; ov[2] = o1[0]; ov[3] = o1[1];
        ov[4] = o2[0]; ov[5] = o2[1]; ov[6] = o3[0]; ov[7] = o3[1];
        *(h8*)&fnorm[ob + (size_t)r * 512 + k * 8] = ov;
    }
}

// ============ kss4: self-similarity, 16x8 tile, vertical px-pairs =========
#define SS_NPX 240
__global__ __launch_bounds__(256) void kss4(const ushort* __restrict__ fnorm,
                                            float* __restrict__ out,
                                            ushort* __restrict__ sspk0) {
    __shared__ ushort tile[2][SS_NPX * 32];   // 2 x 15.36 KB
    int tid = threadIdx.x;
    int w = tid >> 6, lane = tid & 63;
    int s = lane >> 4, q = lane & 15;
    int b, y0, x0;
    tile576(blockIdx.x, b, y0, x0);

    // staging: 960 16B-units (240 px x 4), 4 tasks/thread, swizzled dst
    size_t t_src[4];
    int t_dst[4];
    bool t_ok[4];
#pragma unroll
    for (int k = 0; k < 4; ++k) {
        int task = tid + k * 256;
        t_ok[k] = false; t_src[k] = 0; t_dst[k] = -1;
        if (task < 960) {
            int px = task >> 2, u = task & 3;
            int hr = px / 20, hc = px % 20;
            int gy = y0 + hr - 2, gx = x0 + hc - 2;
            t_dst[k] = px * 32 + ((u ^ ((px >> 1) & 3)) * 8);
            if (gy >= 0 && gy < Hh && gx >= 0 && gx < Ww) {
                t_ok[k] = true;
                t_src[k] = ((size_t)b * HW + (size_t)gy * Ww + gx) * 512 + u * 8;
            }
        }
    }

    float acc0[25], acc1[25];
#pragma unroll
    for (int o = 0; o < 25; ++o) { acc0[o] = 0.f; acc1[o] = 0.f; }

    auto stage = [&](int chunk, int nbuf) {
        short8 v[4];
#pragma unroll
        for (int k = 0; k < 4; ++k) {
            v[k] = (short8)0;
            if (t_ok[k]) v[k] = *(const short8*)(fnorm + t_src[k] + chunk * 32);
        }
#pragma unroll
        for (int k = 0; k < 4; ++k)
            if (t_dst[k] >= 0)
                *(short8*)&tile[nbuf][t_dst[k]] = v[k];
    };

    auto compute = [&](int kb) {
        const ushort* tb = tile[kb];
        auto rd = [&](int px) -> h8 {
            return *(const h8*)&tb[px * 32 + ((s ^ ((px >> 1) & 3)) * 8)];
        };
        int pc0 = (2 * w + 2) * 20 + q + 2;
        h8 c0 = rd(pc0);
        h8 c1 = rd(pc0 + 20);
#pragma unroll
        for (int dxc = 0; dxc < 5; ++dxc) {
#pragma unroll
            for (int dyr = 0; dyr < 6; ++dyr) {
                int pn = (2 * w + dyr) * 20 + q + dxc;
                h8 nv = rd(pn);
                if (dyr < 5) {
                    float a = acc0[dxc * 5 + dyr];
                    a = FDOT2(pair(nv, 0), pair(c0, 0), a);
                    a = FDOT2(pair(nv, 1), pair(c0, 1), a);
                    a = FDOT2(pair(nv, 2), pair(c0, 2), a);
                    a = FDOT2(pair(nv, 3), pair(c0, 3), a);
                    acc0[dxc * 5 + dyr] = a;
                }
                if (dyr > 0) {
                    float a = acc1[dxc * 5 + dyr - 1];
                    a = FDOT2(pair(nv, 0), pair(c1, 0), a);
                    a = FDOT2(pair(nv, 1), pair(c1, 1), a);
                    a = FDOT2(pair(nv, 2), pair(c1, 2), a);
                    a = FDOT2(pair(nv, 3), pair(c1, 3), a);
                    acc1[dxc * 5 + dyr - 1] = a;
                }
            }
        }
    };

    stage(0, 0);
    __syncthreads();
    for (int c = 0; c < 16; ++c) {
        if (c < 15) stage(c + 1, (c + 1) & 1);
        compute(c & 1);
        __syncthreads();
    }

    // reduce across the 4 slabs (lane quarters)
#pragma unroll
    for (int o = 0; o < 25; ++o) {
        float v0 = acc0[o];
        v0 += __shfl_xor(v0, 16);
        v0 += __shfl_xor(v0, 32);
        acc0[o] = v0;
        float v1 = acc1[o];
        v1 += __shfl_xor(v1, 16);
        v1 += __shfl_xor(v1, 32);
        acc1[o] = v1;
    }
    if (s == 0) {
        int gy0 = y0 + 2 * w, gx = x0 + q;
        size_t pix0 = (size_t)b * HW + (size_t)gy0 * Ww + gx;
        size_t ob0 = (size_t)b * OUTC * HW + (size_t)gy0 * Ww + gx;
#pragma unroll
        for (int o = 0; o < 25; ++o) {
            __builtin_nontemporal_store(acc0[o], &out[ob0 + (size_t)o * HW]);
            __builtin_nontemporal_store(acc1[o], &out[ob0 + (size_t)o * HW + Ww]);
        }
        ushort pk0[32], pk1[32];
#pragma unroll
        for (int o = 0; o < 25; ++o) { pk0[o] = f2bf(acc0[o]); pk1[o] = f2bf(acc1[o]); }
#pragma unroll
        for (int o = 25; o < 32; ++o) { pk0[o] = 0; pk1[o] = 0; }
#pragma unroll
        for (int u = 0; u < 4; ++u) {
            *(short8*)&sspk0[pix0 * 32 + u * 8] = *(short8*)&pk0[u * 8];
            *(short8*)&sspk0[(pix0 + Ww) * 32 + u * 8] = *(short8*)&pk1[u * 8];
        }
    }
}

// ============ kconv1m: 25->256 conv, WEIGHTS IN REGISTERS =================
#define C1NPX 180
__global__ __launch_bounds__(512, 2) void kconv1m(const ushort* __restrict__ sspk0,
                                                  const ushort* __restrict__ wpk0,
                                                  const float* __restrict__ b0,
                                                  float* __restrict__ outp,
                                                  ushort* __restrict__ sspk) {
    __shared__ ushort plds[C1NPX * 32];   // 11.52 KB
    int tid = threadIdx.x;
    int lane = tid & 63, wid = tid >> 6;
    int wM = wid >> 1, wN = wid & 1;
    int l15 = lane & 15, l4 = lane >> 4;
    int b, y0, x0;
    tile576(blockIdx.x, b, y0, x0);

    // pixel staging loads (issued first: 2 VMEM ops/thread)
    short8 pv[2]; int pdst[2];
#pragma unroll
    for (int k = 0; k < 2; ++k) {
        int task = tid + k * 512;
        pv[k] = (short8)0; pdst[k] = -1;
        if (task < 720) {
            int px = task >> 2, u = task & 3;
            int iy = px / 18, ix = px % 18;
            int gy = y0 + iy - 1, gx = x0 + ix - 1;
            pdst[k] = px * 32 + (u ^ ((px >> 1) & 3)) * 8;
            if (gy >= 0 && gy < Hh && gx >= 0 && gx < Ww)
                pv[k] = *(const short8*)(sspk0 +
                        ((size_t)b * HW + (size_t)gy * Ww + gx) * 32 + u * 8);
        }
    }

    // A-frag register loads: tap t -> 4 coalesced 1KB loads/wave
    int wslot = l4 ^ ((l15 >> 1) & 3);
    const ushort* abase = wpk0 + (size_t)(wM * 64 + l15) * 32 + wslot * 8;
    short8 sA[4], sB[4];
    auto aload = [&](int t, short8 (&S)[4]) {
#pragma unroll
        for (int mi = 0; mi < 4; ++mi)
            S[mi] = *(const short8*)(abase + (size_t)t * 8192 + mi * 512);
    };

    aload(0, sA);
    aload(1, sB);

    // write pixels to LDS (compiler auto-waits on pv), then one barrier
#pragma unroll
    for (int k = 0; k < 2; ++k)
        if (pdst[k] >= 0) *(short8*)&plds[pdst[k]] = pv[k];
    LGKM0();
    __builtin_amdgcn_s_barrier();

    f32x4 acc[4][4];
#pragma unroll
    for (int mi = 0; mi < 4; ++mi)
#pragma unroll
        for (int ni = 0; ni < 4; ++ni)
            acc[mi][ni] = (f32x4)0.f;

    auto compute = [&](const short8 (&S)[4], int ky, int kx) {
        short8 bv[4];
#pragma unroll
        for (int ni = 0; ni < 4; ++ni) {
            int ipx = (wN * 4 + ni + ky) * 18 + l15 + kx;
            bv[ni] = *(const short8*)&plds[ipx * 32
                    + ((l4 ^ ((ipx >> 1) & 3)) * 8)];
        }
#pragma unroll
        for (int mi = 0; mi < 4; ++mi)
#pragma unroll
            for (int ni = 0; ni < 4; ++ni)
                acc[mi][ni] = __builtin_amdgcn_mfma_f32_16x16x32_bf16(
                    S[mi], bv[ni], acc[mi][ni], 0, 0, 0);
    };

    // tap loop, barrier-free; A dbuf: even taps sA, odd taps sB
#pragma unroll
    for (int t = 0; t < 9; ++t) {
        if (t < 8) { VMCNT(4); } else { VMCNT(0); }
        int ky = t / 3, kx = t % 3;
        if ((t & 1) == 0) {
            compute(sA, ky, kx);
            if (t < 7) aload(t + 2, sA);
        } else {
            compute(sB, ky, kx);
            if (t < 7) aload(t + 2, sB);
        }
    }

    size_t ob = (size_t)b * OUTC * HW + (size_t)25 * HW;
    size_t pb = (size_t)b * HW;
#pragma unroll
    for (int mi = 0; mi < 4; ++mi)
#pragma unroll
        for (int ni = 0; ni < 4; ++ni) {
            int gy = y0 + wN * 4 + ni, gx = x0 + l15;
            int oc_b = wM * 64 + mi * 16 + l4 * 4;
            short4v hv;
#pragma unroll
            for (int r = 0; r < 4; ++r) {
                float v = fmaxf(acc[mi][ni][r] + b0[oc_b + r], 0.f);
                __builtin_nontemporal_store(v,
                    &outp[ob + (size_t)(oc_b + r) * HW + (size_t)gy * Ww + gx]);
                hv[r] = (short)f2bf(v);
            }
            *(short4v*)&sspk[(pb + (size_t)gy * Ww + gx) * 256 + oc_b] = hv;
        }
}

// ============ kconv2n: 256->128 conv, 16x8, WEIGHTS IN REGISTERS ==========
// R8 structure + bijective XCD swizzle (576 blocks, one batch per XCD).
#define NPX2 180
__global__ __launch_bounds__(256, 2) void kconv2n(const ushort* __restrict__ sspk,
                                                  const ushort* __restrict__ wpk,
                                                  const float* __restrict__ b1,
                                                  const ushort* __restrict__ zpad,
                                                  float* __restrict__ outp) {
    __shared__ ushort plds[2][6144];       // 2 x 12 KB (768 units incl pad)
    int tid = threadIdx.x;
    int lane = tid & 63, wid = tid >> 6;
    int wM = wid >> 1, wN = wid & 1;
    int l15 = lane & 15, l4 = lane >> 4;
    int b, y0, x0;
    tile576(blockIdx.x, b, y0, x0);

    f32x4 acc[4][4];
#pragma unroll
    for (int mi = 0; mi < 4; ++mi)
#pragma unroll
        for (int ni = 0; ni < 4; ++ni)
            acc[mi][ni] = (f32x4)0.f;

    // pixel DMA prep: 3 tasks/thread; source pre-swizzled (unit u = slot ^
    // ((px>>1)&3)) so linear DMA reproduces the swizzled LDS layout.
    const ushort* p_src[3];
    int p_ok[3];
#pragma unroll
    for (int k = 0; k < 3; ++k) {
        int task = tid + k * 256;
        int px = task >> 2, slot = task & 3;
        int u = slot ^ ((px >> 1) & 3);
        int iy = px / 18, ix = px % 18;
        int gy = y0 + iy - 1, gx = x0 + ix - 1;
        bool ok = (px < NPX2) && gy >= 0 && gy < Hh && gx >= 0 && gx < Ww;
        p_ok[k] = ok ? 1 : 0;
        p_src[k] = ok ? (sspk + ((size_t)b * HW + (size_t)gy * Ww + gx) * 256
                         + u * 8)
                      : zpad;
    }
    auto pstage = [&](int c, int buf) {       // 3 ops/wave (vmcnt P=3)
#pragma unroll
        for (int k = 0; k < 3; ++k)
            __builtin_amdgcn_global_load_lds(
                (gu32*)(p_src[k] + (p_ok[k] ? c * 32 : 0)),
                (lu32*)&plds[buf][(k * 256 + wid * 64) * 8], 16, 0, 0);
    };

    // A-frag register loads: group g -> 12 x global_load_dwordx4 (coalesced
    // 1 KB/instr), j = kx*4+mi
    int wslot = l4 ^ ((l15 >> 1) & 3);
    const ushort* abase = wpk + (size_t)(wM * 64 + l15) * 32 + wslot * 8;
    short8 sA[12], sB[12];
    auto aload = [&](int g, short8 (&S)[12]) {
#pragma unroll
        for (int kx = 0; kx < 3; ++kx)
#pragma unroll
            for (int mi = 0; mi < 4; ++mi)
                S[kx * 4 + mi] = *(const short8*)(abase + (size_t)g * 12288
                                                  + kx * 4096 + mi * 512);
    };
    auto compute = [&](const short8 (&S)[12], const ushort* lbase, int ky) {
#pragma unroll
        for (int kx = 0; kx < 3; ++kx) {
            short8 bv[4];
#pragma unroll
            for (int ni = 0; ni < 4; ++ni) {
                int oy = wN * 4 + ni;
                int ipx = (oy + ky) * 18 + l15 + kx;
                bv[ni] = *(const short8*)&lbase[ipx * 32
                        + ((l4 ^ ((ipx >> 1) & 3)) * 8)];
            }
#pragma unroll
            for (int mi = 0; mi < 4; ++mi)
#pragma unroll
                for (int ni = 0; ni < 4; ++ni)
                    acc[mi][ni] = __builtin_amdgcn_mfma_f32_16x16x32_bf16(
                        S[kx * 4 + mi], bv[ni], acc[mi][ni], 0, 0, 0);
        }
    };

    // Per-chunk schedule (steady-state outstanding at entry:
    // A_{3c}[12], P_c[3], A_{3c+1}[12]):
    //   VM(12): retire P_c + A_{3c}   -> barrier -> ky0(Scur)
    //   aload(3c+2 -> Scur); VM(12): retire A_{3c+1} -> ky1(Salt)
    //   aload(3c+3 -> Salt); pstage(c+1); VM(15): retire A_{3c+2} -> ky2(Scur)
    //   aload(3c+4 -> Scur)
    auto chunk = [&](int c, short8 (&Scur)[12], short8 (&Salt)[12], bool last) {
        const ushort* lbase = plds[c & 1];
        VMCNT(12);
        __builtin_amdgcn_s_barrier();
        compute(Scur, lbase, 0);
        aload(3 * c + 2, Scur);
        VMCNT(12);
        compute(Salt, lbase, 1);
        if (!last) {
            aload(3 * c + 3, Salt);
            pstage(c + 1, (c + 1) & 1);
            VMCNT(15);
        } else {
            VMCNT(0);
        }
        compute(Scur, lbase, 2);
        if (!last) aload(3 * c + 4, Scur);
    };

    // prologue: P0, A0 -> sA, A1 -> sB
    pstage(0, 0);
    aload(0, sA);
    aload(1, sB);

    for (int c2 = 0; c2 < 4; ++c2) {
        chunk(2 * c2,     sA, sB, false);
        chunk(2 * c2 + 1, sB, sA, c2 == 3);
    }

    size_t ob = (size_t)b * OUTC * HW + (size_t)281 * HW;
#pragma unroll
    for (int mi = 0; mi < 4; ++mi)
#pragma unroll
        for (int ni = 0; ni < 4; ++ni) {
            int gy = y0 + wN * 4 + ni, gx = x0 + l15;
#pragma unroll
            for (int r = 0; r < 4; ++r) {
                int oc = wM * 64 + mi * 16 + l4 * 4 + r;
                float v = acc[mi][ni][r] + b1[oc];
                __builtin_nontemporal_store(fmaxf(v, 0.f),
                    &outp[ob + (size_t)oc * HW + (size_t)gy * Ww + gx]);
            }
        }
}

extern "C" void kernel_launch(void* const* d_in, const int* in_sizes, int n_in,
                              void* d_out, int out_size, void* d_ws, size_t ws_size,
                              hipStream_t stream) {
    const float* feat = (const float*)d_in[0];
    const float* w0   = (const float*)d_in[1];
    const float* b0   = (const float*)d_in[2];
    const float* w1   = (const float*)d_in[3];
    const float* b1   = (const float*)d_in[4];
    float* out = (float*)d_out;

    // ws: wpk0 (147456) | wpk1 (589824) | sspk (37748736) | fnorm (75497472)
    //     | sspk0 (4718592) | zpad (64)
    ushort* wpk0  = (ushort*)d_ws;
    ushort* wpk1  = (ushort*)((char*)d_ws + 147456);
    ushort* sspk  = (ushort*)((char*)d_ws + 147456 + 589824);
    ushort* fnorm = (ushort*)((char*)d_ws + 147456 + 589824 + 37748736);
    ushort* sspk0 = (ushort*)((char*)d_ws + 147456 + 589824 + 37748736
                              + 75497472);
    ushort* zpad  = (ushort*)((char*)d_ws + 147456 + 589824 + 37748736
                              + 75497472 + 4718592);

    hipLaunchKernelGGL(kpackw,  dim3(2304 + 1440), dim3(256), 0, stream,
                       feat, fnorm, w0, w1, wpk0, wpk1, zpad);
    hipLaunchKernelGGL(kss4,    dim3(576), dim3(256), 0, stream, fnorm, out, sspk0);
    hipLaunchKernelGGL(kconv1m, dim3(576), dim3(512), 0, stream, sspk0, wpk0, b0, out, sspk);
    hipLaunchKernelGGL(kconv2n, dim3(576), dim3(256), 0, stream, sspk, wpk1, b1, zpad, out);
}